// Round 9
// baseline (1580.664 us; speedup 1.0000x reference)
//
#include <hip/hip_runtime.h>
#include <hip/hip_bf16.h>
#include <math.h>

#define BB 16
#define TT 360
#define VV 25
#define NN 9000
#define EE 72000
#define HH 128
#define RR (NN * BB)    // 144000 rows total
#define CROWS 18000     // rows per chunk (9000 nodes x 2 batches)
#define TPC 282         // tiles per chunk (32 nodes/tile, last tile 8 nodes)
#define NT2 (8 * TPC)   // 2256 blocks for k_layer
#define NPART0 563      // partial-stats blocks for k_mm2 (L0)
#define NCLSS 12
#define EPSB 1e-5f

// chunked activation layout: row R(n,b) = (b>>1)*18000 + n*2 + (b&1)

typedef short short4v __attribute__((ext_vector_type(4)));
typedef short short8 __attribute__((ext_vector_type(8)));
typedef float float16v __attribute__((ext_vector_type(16)));
typedef unsigned short ushort_t;

__device__ __forceinline__ float bf2f(ushort_t u) {
    union { unsigned i; float f; } w;
    w.i = ((unsigned)u) << 16;
    return w.f;
}
__device__ __forceinline__ ushort_t f2bf(float f) {
    union { float f; unsigned i; } w;
    w.f = f;
    unsigned r = (w.i + 0x7FFF + ((w.i >> 16) & 1)) >> 16;  // RNE
    return (ushort_t)r;
}

// ---------------- graph preprocessing ----------------

__global__ void k_count(const int* __restrict__ ei, int* __restrict__ counts) {
    int e = blockIdx.x * 256 + threadIdx.x;
    if (e < EE) atomicAdd(&counts[ei[EE + e]], 1);
}

__global__ void k_dinv(const int* __restrict__ counts, float* __restrict__ dinv) {
    int n = blockIdx.x * 256 + threadIdx.x;
    if (n < NN) dinv[n] = rsqrtf((float)(counts[n] + 1));
}

__global__ void k_scan(const int* __restrict__ counts, int* __restrict__ rowptr) {
    __shared__ int part[1024];
    int t = threadIdx.x;
    int base = t * 9;
    int loc[9];
    int s = 0;
#pragma unroll
    for (int i = 0; i < 9; i++) {
        int idx = base + i;
        int v = (idx < NN) ? counts[idx] : 0;
        loc[i] = s;
        s += v;
    }
    part[t] = s;
    __syncthreads();
    for (int d = 1; d < 1024; d <<= 1) {
        int v = (t >= d) ? part[t - d] : 0;
        __syncthreads();
        part[t] += v;
        __syncthreads();
    }
    int excl = (t == 0) ? 0 : part[t - 1];
#pragma unroll
    for (int i = 0; i < 9; i++) {
        int idx = base + i;
        if (idx < NN) rowptr[idx] = excl + loc[i];
    }
    if (t == 1023) rowptr[NN] = part[1023];
}

__global__ void k_fill(const int* __restrict__ ei, const int* __restrict__ rowptr,
                       int* __restrict__ cursor, const float* __restrict__ dinv,
                       int2* __restrict__ csr) {
    int e = blockIdx.x * 256 + threadIdx.x;
    if (e >= EE) return;
    int s = ei[e], d = ei[EE + e];
    int slot = rowptr[d] + atomicAdd(&cursor[d], 1);
    int2 e2;
    e2.x = s;
    e2.y = __float_as_int(dinv[s] * dinv[d]);
    csr[slot] = e2;
}

// pre-convert the 11 layer weight matrices to bf16 W^T images: Wbf[l][c*128+k]
__global__ void k_wcvt(const float* __restrict__ sW, const float* __restrict__ mW,
                       const float* __restrict__ aW, ushort_t* __restrict__ Wbf) {
    int idx = blockIdx.x * 256 + threadIdx.x;
    if (idx >= 11 * 16384) return;
    int l = idx >> 14, r = idx & 16383;
    int k = r >> 7, c = r & 127;
    const float* src = (l < 2) ? sW + (size_t)l * 16384
                               : ((l == 2) ? mW : aW + (size_t)(l - 3) * 16384);
    Wbf[(size_t)l * 16384 + c * 128 + k] = f2bf(src[k * 128 + c]);
}

// ---------------- L0 propagation of raw x (2 channels) ----------------
__global__ void k_prop2(const float* __restrict__ x, float* __restrict__ P0,
                        const int* __restrict__ rowptr, const int2* __restrict__ csr,
                        const float* __restrict__ dinv) {
    int n = blockIdx.x * 256 + threadIdx.x;
    if (n >= NN) return;
    int b = blockIdx.y;
    const float* xb = x + (size_t)b * NN * 2;
    float d2 = dinv[n] * dinv[n];
    float a0 = d2 * xb[2 * n], a1 = d2 * xb[2 * n + 1];
    int beg = rowptr[n], end = rowptr[n + 1];
    for (int j = beg; j < end; j++) {
        int2 e2 = csr[j];
        int s = e2.x;
        float cf = __int_as_float(e2.y);
        a0 += cf * xb[2 * s];
        a1 += cf * xb[2 * s + 1];
    }
    float* Pb = P0 + (size_t)(n * BB + b) * 2;
    Pb[0] = a0;
    Pb[1] = a1;
}

// L0 matmul (K=2), writes chunked layout, fused BN partial stats pS[c][part].
__global__ void __launch_bounds__(256) k_mm2(const float* __restrict__ P0,
                                             ushort_t* __restrict__ A,
                                             const float* __restrict__ W,
                                             const float* __restrict__ bias,
                                             float* __restrict__ pS1, float* __restrict__ pS2) {
    __shared__ float L1[256][8], L2[256][8];
    int t = threadIdx.x;
    int cg = t & 15, c8 = cg * 8;
    float wv0[8], wv1[8], bv[8];
#pragma unroll
    for (int j = 0; j < 8; j++) {
        wv0[j] = W[c8 + j];
        wv1[j] = W[HH + c8 + j];
        bv[j] = bias[c8 + j];
    }
    float s1[8], s2[8];
#pragma unroll
    for (int j = 0; j < 8; j++) { s1[j] = 0.f; s2[j] = 0.f; }
    for (int idx = blockIdx.x * 256 + t; idx < RR * 16; idx += gridDim.x * 256) {
        int Rr = idx >> 4;
        int q = Rr / CROWS;
        int rr = Rr - q * CROWS;
        int n = rr >> 1;
        int b = q * 2 + (rr & 1);
        float p0 = P0[((size_t)n * BB + b) * 2], p1 = P0[((size_t)n * BB + b) * 2 + 1];
        short8 o;
#pragma unroll
        for (int j = 0; j < 8; j++) {
            float v = p0 * wv0[j] + p1 * wv1[j] + bv[j];
            s1[j] += v;
            s2[j] += v * v;
            o[j] = (short)f2bf(v);
        }
        *(short8*)(A + (size_t)Rr * HH + c8) = o;
    }
#pragma unroll
    for (int j = 0; j < 8; j++) { L1[t][j] = s1[j]; L2[t][j] = s2[j]; }
    __syncthreads();
    if (t < 16) {
#pragma unroll
        for (int g = 1; g < 16; g++)
#pragma unroll
            for (int j = 0; j < 8; j++) {
                s1[j] = (g == 1 ? L1[t][j] : s1[j]) + L1[t + 16 * g][j];
                s2[j] = (g == 1 ? L2[t][j] : s2[j]) + L2[t + 16 * g][j];
            }
#pragma unroll
        for (int j = 0; j < 8; j++) {
            pS1[(size_t)(t * 8 + j) * NPART0 + blockIdx.x] = s1[j];
            pS2[(size_t)(t * 8 + j) * NPART0 + blockIdx.x] = s2[j];
        }
    }
}

// ---------------- FUSED layer: wave-per-node gather -> LDS -> MFMA -> A + stats ----
// chunked (2 batches, 4.6MB, L2-resident, blockIdx&7 XCD-routed); 32 nodes/block.
__global__ void __launch_bounds__(256) k_layer(const ushort_t* __restrict__ h,
                                               ushort_t* __restrict__ A,
                                               const ushort_t* __restrict__ Wbf,
                                               const float* __restrict__ bias,
                                               const int* __restrict__ rowptr,
                                               const int2* __restrict__ csr,
                                               const float* __restrict__ dinv,
                                               const float* __restrict__ scale,
                                               const float* __restrict__ shiftv, int shn,
                                               float* __restrict__ pS1,
                                               float* __restrict__ pS2) {
    __shared__ ushort_t pt[64 * 128];           // swizzled P tile, 16 KB
    __shared__ float rb1[4][128], rb2[4][128];  // 4 KB stats reduction
    int t = threadIdx.x;
    int q = blockIdx.x & 7;      // chunk -> XCD routing (round-7-proven)
    int tile = blockIdx.x >> 3;  // 0..281
    int node0 = tile * 32;
    int vrows = (NN - node0) * 2;
    if (vrows > 64) vrows = 64;
    const ushort_t* hb = h + (size_t)q * CROWS * HH;

    int wv = t >> 6, l = t & 63;
    int bi = l >> 5, cg = l & 31, c4 = cg * 4;  // batch-in-chunk, 4-channel group
    float sc[4], sh[4];
#pragma unroll
    for (int j = 0; j < 4; j++) {
        sc[j] = scale[c4 + j];
        sh[j] = shiftv[c4 + j];
    }
    // ---- phase 1: wave wv gathers nodes node0+wv*8 .. +7 (wave-uniform edge loops) ----
    for (int i = 0; i < 8; i++) {
        int nl = wv * 8 + i;
        int n = node0 + nl;
        float acc[4] = {0.f, 0.f, 0.f, 0.f};
        if (n < NN) {
            int pn = n + shn;
            if (pn >= NN) pn -= NN;
            float d2 = dinv[n] * dinv[n];
            {
                short4v v = *(const short4v*)(hb + ((size_t)pn * 2 + bi) * HH + c4);
#pragma unroll
                for (int j = 0; j < 4; j++) {
                    float f = bf2f((ushort_t)v[j]) * sc[j] + sh[j];
                    acc[j] = d2 * fmaxf(f, 0.f);
                }
            }
            int beg = rowptr[n], end = rowptr[n + 1];
            for (int e = beg; e < end; e++) {
                int2 e2 = csr[e];
                int s = e2.x;
                float cf = __int_as_float(e2.y);
                int ps = s + shn;
                if (ps >= NN) ps -= NN;
                short4v v = *(const short4v*)(hb + ((size_t)ps * 2 + bi) * HH + c4);
#pragma unroll
                for (int j = 0; j < 4; j++) {
                    float f = bf2f((ushort_t)v[j]) * sc[j] + sh[j];
                    acc[j] += cf * fmaxf(f, 0.f);
                }
            }
        }
        short4v o;
#pragma unroll
        for (int j = 0; j < 4; j++) o[j] = (short)f2bf(acc[j]);
        int row = nl * 2 + bi;
        int G = cg >> 1, sfx = cg & 1;
        *(short4v*)(pt + row * 128 + ((G ^ (row & 15)) << 3) + sfx * 4) = o;
    }
    __syncthreads();
    // ---- phase 2: MFMA (A-frags from LDS, B-frags from global W^T bf16) ----
    int w = t >> 6;
    int rw = w >> 1, cw = w & 1;  // 32-row half x 64-col half
    int lr = l & 31, hi = l >> 5;
    float16v acc2[2];
#pragma unroll
    for (int ct = 0; ct < 2; ct++) acc2[ct] = (float16v)(0.0f);
    const ushort_t* Wc0 = Wbf + (size_t)(cw * 64 + lr) * HH;
    const ushort_t* Wc1 = Wbf + (size_t)(cw * 64 + 32 + lr) * HH;
#pragma unroll
    for (int ks = 0; ks < 8; ks++) {
        int koff = ks * 16 + hi * 8;
        int chx = (ks * 2 + hi) ^ (lr & 15);
        short8 a0 = *(const short8*)(pt + (rw * 32 + lr) * 128 + chx * 8);
        short8 b0 = *(const short8*)(Wc0 + koff);
        short8 b1 = *(const short8*)(Wc1 + koff);
        acc2[0] = __builtin_amdgcn_mfma_f32_32x32x16_bf16(a0, b0, acc2[0], 0, 0, 0);
        acc2[1] = __builtin_amdgcn_mfma_f32_32x32x16_bf16(a0, b1, acc2[1], 0, 0, 0);
    }
    // ---- epilogue: bias, stats, store bf16 (guard tail rows) ----
    float bv[2] = {bias[cw * 64 + lr], bias[cw * 64 + 32 + lr]};
    float s1a[2] = {0.f, 0.f}, s2a[2] = {0.f, 0.f};
    size_t gbase = (size_t)q * CROWS + (size_t)tile * 64;
#pragma unroll
    for (int ct = 0; ct < 2; ct++) {
        int c = cw * 64 + ct * 32 + lr;
#pragma unroll
        for (int g = 0; g < 16; g++) {
            int row = rw * 32 + (g & 3) + 8 * (g >> 2) + 4 * hi;
            if (row < vrows) {
                float v = acc2[ct][g] + bv[ct];
                s1a[ct] += v;
                s2a[ct] += v * v;
                A[(gbase + row) * HH + c] = f2bf(v);
            }
        }
    }
    int slot = rw * 2 + hi;
#pragma unroll
    for (int ct = 0; ct < 2; ct++) {
        int cidx = cw * 64 + ct * 32 + lr;
        rb1[slot][cidx] = s1a[ct];
        rb2[slot][cidx] = s2a[ct];
    }
    __syncthreads();
    if (t < 128) {
        float a1 = rb1[0][t] + rb1[1][t] + rb1[2][t] + rb1[3][t];
        float a2 = rb2[0][t] + rb2[1][t] + rb2[2][t] + rb2[3][t];
        pS1[(size_t)t * NT2 + blockIdx.x] = a1;  // transposed: [channel][block]
        pS2[(size_t)t * NT2 + blockIdx.x] = a2;
    }
}

// finalize BN affine from transposed partials: one block per channel, coalesced rows
__global__ void __launch_bounds__(256) k_bnfin(const float* __restrict__ pS1,
                                               const float* __restrict__ pS2, int npart,
                                               const float* __restrict__ g,
                                               const float* __restrict__ be,
                                               float* __restrict__ scale,
                                               float* __restrict__ shiftv) {
    __shared__ float R1[256], R2[256];
    int c = blockIdx.x;
    int t = threadIdx.x;
    const float* p1 = pS1 + (size_t)c * npart;
    const float* p2 = pS2 + (size_t)c * npart;
    float s1 = 0.f, s2 = 0.f;
    for (int i = t; i < npart; i += 256) {
        s1 += p1[i];
        s2 += p2[i];
    }
    R1[t] = s1;
    R2[t] = s2;
    __syncthreads();
    for (int d = 128; d > 0; d >>= 1) {
        if (t < d) {
            R1[t] += R1[t + d];
            R2[t] += R2[t + d];
        }
        __syncthreads();
    }
    if (t == 0) {
        float inv = 1.0f / (float)RR;
        float mu = R1[0] * inv;
        float var = R2[0] * inv - mu * mu;
        float sc = g[c] * rsqrtf(var + EPSB);
        scale[c] = sc;
        shiftv[c] = be[c] - mu * sc;
    }
}

// fused BN-affine + ReLU + mean-pool (per head), chunked layout reads
__global__ void __launch_bounds__(256) k_relu_pool(const ushort_t* __restrict__ A,
                                                   const float* __restrict__ scale,
                                                   const float* __restrict__ shiftv,
                                                   float* __restrict__ pooled) {
    __shared__ float L[256][8];
    int t = threadIdx.x;
    int b = blockIdx.y;
    int n0 = blockIdx.x * 250;
    int ng = t >> 4, c8 = (t & 15) * 8;
    float sc[8], sh[8];
#pragma unroll
    for (int j = 0; j < 8; j++) {
        sc[j] = scale[c8 + j];
        sh[j] = shiftv[c8 + j];
    }
    const ushort_t* Ab = A + ((size_t)(b >> 1) * CROWS + (b & 1)) * HH;
    float acc[8];
#pragma unroll
    for (int j = 0; j < 8; j++) acc[j] = 0.f;
    for (int n = n0 + ng; n < n0 + 250; n += 16) {
        short8 v = *(const short8*)(Ab + (size_t)n * 2 * HH + c8);
#pragma unroll
        for (int j = 0; j < 8; j++) {
            float f = bf2f((ushort_t)v[j]) * sc[j] + sh[j];
            acc[j] += fmaxf(f, 0.f);
        }
    }
#pragma unroll
    for (int j = 0; j < 8; j++) L[t][j] = acc[j];
    __syncthreads();
    if (ng == 0) {
#pragma unroll
        for (int g = 1; g < 16; g++)
#pragma unroll
            for (int j = 0; j < 8; j++) acc[j] += L[t + 16 * g][j];
#pragma unroll
        for (int j = 0; j < 8; j++) atomicAdd(&pooled[b * HH + t * 8 + j], acc[j]);
    }
}

// all 9 heads: linear + log_softmax
__global__ void __launch_bounds__(192) k_head_all(const float* __restrict__ pooled,
                                                  const float* __restrict__ main_Wf,
                                                  const float* __restrict__ main_bf,
                                                  const float* __restrict__ aux_Wf,
                                                  const float* __restrict__ aux_bf,
                                                  float* __restrict__ out) {
    int hd = blockIdx.x;
    const float* Wf = hd ? aux_Wf + (size_t)(hd - 1) * HH * NCLSS : main_Wf;
    const float* bf = hd ? aux_bf + (hd - 1) * NCLSS : main_bf;
    const float* pl = pooled + (size_t)hd * BB * HH;
    __shared__ float z[BB][NCLSS];
    __shared__ float lse[BB];
    int t = threadIdx.x;
    int b = t / NCLSS, j = t % NCLSS;
    if (t < BB * NCLSS) {
        float acc = bf[j];
        const float invn = 1.0f / NN;
        for (int c = 0; c < HH; c++) acc += pl[b * HH + c] * invn * Wf[c * NCLSS + j];
        z[b][j] = acc;
    }
    __syncthreads();
    if (t < BB) {
        float m = -1e30f;
        for (int j2 = 0; j2 < NCLSS; j2++) m = fmaxf(m, z[t][j2]);
        float s = 0.f;
        for (int j2 = 0; j2 < NCLSS; j2++) s += expf(z[t][j2] - m);
        lse[t] = m + logf(s);
    }
    __syncthreads();
    if (t < BB * NCLSS) {
        float* o = hd ? out + BB * NCLSS + ((size_t)b * 8 + (hd - 1)) * NCLSS + j
                      : out + b * NCLSS + j;
        *o = z[b][j] - lse[b];
    }
}

// ---------------- host ----------------

extern "C" void kernel_launch(void* const* d_in, const int* in_sizes, int n_in, void* d_out,
                              int out_size, void* d_ws, size_t ws_size, hipStream_t stream) {
    const float* x = (const float*)d_in[0];
    const int* ei = (const int*)d_in[1];
    const float* W_in = (const float*)d_in[2];
    const float* b_in = (const float*)d_in[3];
    const float* g_in = (const float*)d_in[4];
    const float* be_in = (const float*)d_in[5];
    const float* shared_W = (const float*)d_in[6];
    const float* shared_b = (const float*)d_in[7];
    const float* shared_g = (const float*)d_in[8];
    const float* shared_be = (const float*)d_in[9];
    const float* main_Wg = (const float*)d_in[10];
    const float* main_bg = (const float*)d_in[11];
    const float* main_g = (const float*)d_in[12];
    const float* main_be = (const float*)d_in[13];
    const float* main_Wf = (const float*)d_in[14];
    const float* main_bf = (const float*)d_in[15];
    const float* aux_Wg = (const float*)d_in[16];
    const float* aux_bg = (const float*)d_in[17];
    const float* aux_g = (const float*)d_in[18];
    const float* aux_be = (const float*)d_in[19];
    const float* aux_Wf = (const float*)d_in[20];
    const float* aux_bf = (const float*)d_in[21];
    float* out = (float*)d_out;

    char* w = (char*)d_ws;
    const size_t BIG = (size_t)RR * HH * 2;
    ushort_t* U = (ushort_t*)w;  w += BIG;
    ushort_t* V = (ushort_t*)w;  w += BIG;
    float* P0 = (float*)w;       w += (size_t)RR * 2 * 4;
    ushort_t* Wbf = (ushort_t*)w; w += (size_t)11 * 16384 * 2;
    int2* csr = (int2*)w;        w += (size_t)EE * 8;
    int* counts = (int*)w;       w += NN * 4;
    int* cursor = (int*)w;       w += NN * 4;
    float* dinv = (float*)w;     w += NN * 4;
    int* rowptr = (int*)w;       w += 36016;
    float* pS1 = (float*)w;      w += (size_t)HH * NT2 * 4;
    float* pS2 = (float*)w;      w += (size_t)HH * NT2 * 4;
    float* pooled = (float*)w;   w += 9 * BB * HH * 4;
    float* tscale = (float*)w;   w += 512;
    float* tshift = (float*)w;   w += 512;
    float* hscale = (float*)w;   w += 512;
    float* hshift = (float*)w;   w += 512;

    hipMemsetAsync(counts, 0, 2 * NN * 4, stream);
    hipMemsetAsync(pooled, 0, 9 * BB * HH * 4, stream);

    k_count<<<(EE + 255) / 256, 256, 0, stream>>>(ei, counts);
    k_dinv<<<(NN + 255) / 256, 256, 0, stream>>>(counts, dinv);
    k_scan<<<1, 1024, 0, stream>>>(counts, rowptr);
    k_fill<<<(EE + 255) / 256, 256, 0, stream>>>(ei, rowptr, cursor, dinv, csr);
    k_wcvt<<<(11 * 16384 + 255) / 256, 256, 0, stream>>>(shared_W, main_Wg, aux_Wg, Wbf);

    // L0
    {
        dim3 g((NN + 255) / 256, BB);
        k_prop2<<<g, 256, 0, stream>>>(x, P0, rowptr, csr, dinv);
        k_mm2<<<NPART0, 256, 0, stream>>>(P0, U, W_in, b_in, pS1, pS2);
        k_bnfin<<<HH, 256, 0, stream>>>(pS1, pS2, NPART0, g_in, be_in, tscale, tshift);
    }

    // shared trunk layers (fused prop+matmul)
    ushort_t* hcur = U;
    ushort_t* hnext = V;
    for (int l = 0; l < 2; l++) {
        k_layer<<<NT2, 256, 0, stream>>>(hcur, hnext, Wbf + (size_t)l * 16384,
                                         shared_b + l * HH, rowptr, csr, dinv,
                                         tscale, tshift, 0, pS1, pS2);
        k_bnfin<<<HH, 256, 0, stream>>>(pS1, pS2, NT2, shared_g + l * HH, shared_be + l * HH,
                                        tscale, tshift);
        ushort_t* tmp = hcur; hcur = hnext; hnext = tmp;
    }

    // heads
    for (int hd = 0; hd < 9; hd++) {
        int shift = hd * 1000;
        const ushort_t* Wg = Wbf + (size_t)(2 + hd) * 16384;
        const float* bg = (hd == 0) ? main_bg : aux_bg + (hd - 1) * HH;
        const float* gg = (hd == 0) ? main_g : aux_g + (hd - 1) * HH;
        const float* be = (hd == 0) ? main_be : aux_be + (hd - 1) * HH;

        k_layer<<<NT2, 256, 0, stream>>>(hcur, hnext, Wg, bg, rowptr, csr, dinv,
                                         tscale, tshift, shift, pS1, pS2);
        k_bnfin<<<HH, 256, 0, stream>>>(pS1, pS2, NT2, gg, be, hscale, hshift);
        dim3 gp(36, BB);
        k_relu_pool<<<gp, 256, 0, stream>>>(hnext, hscale, hshift, pooled + (size_t)hd * BB * HH);
    }
    k_head_all<<<9, 192, 0, stream>>>(pooled, main_Wf, main_bf, aux_Wf, aux_bf, out);
}

// Round 10
// 1379.243 us; speedup vs baseline: 1.1460x; 1.1460x over previous
//
#include <hip/hip_runtime.h>
#include <hip/hip_bf16.h>
#include <math.h>

#define BB 16
#define TT 360
#define VV 25
#define NN 9000
#define EE 72000
#define HH 128
#define RR (NN * BB)       // 144000 rows total
#define CROWS 18000        // rows per chunk (9000 nodes x 2 batches)
#define NTILES (RR / 64)   // 2250 tiles of 64 rows for k_mfma2 (exact)
#define NPART0 563         // partial-stats blocks for k_mm2 (L0)
#define NCLSS 12
#define EPSB 1e-5f

// chunked activation layout: row R(n,b) = (b>>1)*CROWS + n*2 + (b&1)

typedef short short4v __attribute__((ext_vector_type(4)));
typedef short short8 __attribute__((ext_vector_type(8)));
typedef float float16v __attribute__((ext_vector_type(16)));
typedef unsigned short ushort_t;

__device__ __forceinline__ float bf2f(ushort_t u) {
    union { unsigned i; float f; } w;
    w.i = ((unsigned)u) << 16;
    return w.f;
}
__device__ __forceinline__ ushort_t f2bf(float f) {
    union { float f; unsigned i; } w;
    w.f = f;
    unsigned r = (w.i + 0x7FFF + ((w.i >> 16) & 1)) >> 16;  // RNE
    return (ushort_t)r;
}

// ---------------- graph preprocessing ----------------

__global__ void k_count(const int* __restrict__ ei, int* __restrict__ counts) {
    int e = blockIdx.x * 256 + threadIdx.x;
    if (e < EE) atomicAdd(&counts[ei[EE + e]], 1);
}

__global__ void k_dinv(const int* __restrict__ counts, float* __restrict__ dinv) {
    int n = blockIdx.x * 256 + threadIdx.x;
    if (n < NN) dinv[n] = rsqrtf((float)(counts[n] + 1));
}

__global__ void k_scan(const int* __restrict__ counts, int* __restrict__ rowptr) {
    __shared__ int part[1024];
    int t = threadIdx.x;
    int base = t * 9;
    int loc[9];
    int s = 0;
#pragma unroll
    for (int i = 0; i < 9; i++) {
        int idx = base + i;
        int v = (idx < NN) ? counts[idx] : 0;
        loc[i] = s;
        s += v;
    }
    part[t] = s;
    __syncthreads();
    for (int d = 1; d < 1024; d <<= 1) {
        int v = (t >= d) ? part[t - d] : 0;
        __syncthreads();
        part[t] += v;
        __syncthreads();
    }
    int excl = (t == 0) ? 0 : part[t - 1];
#pragma unroll
    for (int i = 0; i < 9; i++) {
        int idx = base + i;
        if (idx < NN) rowptr[idx] = excl + loc[i];
    }
    if (t == 1023) rowptr[NN] = part[1023];
}

__global__ void k_fill(const int* __restrict__ ei, const int* __restrict__ rowptr,
                       int* __restrict__ cursor, const float* __restrict__ dinv,
                       int2* __restrict__ csr) {
    int e = blockIdx.x * 256 + threadIdx.x;
    if (e >= EE) return;
    int s = ei[e], d = ei[EE + e];
    int slot = rowptr[d] + atomicAdd(&cursor[d], 1);
    int2 e2;
    e2.x = s;
    e2.y = __float_as_int(dinv[s] * dinv[d]);
    csr[slot] = e2;
}

// pre-convert the 11 layer weight matrices to bf16 W^T images: Wbf[l][c*128+k]
__global__ void k_wcvt(const float* __restrict__ sW, const float* __restrict__ mW,
                       const float* __restrict__ aW, ushort_t* __restrict__ Wbf) {
    int idx = blockIdx.x * 256 + threadIdx.x;
    if (idx >= 11 * 16384) return;
    int l = idx >> 14, r = idx & 16383;
    int k = r >> 7, c = r & 127;
    const float* src = (l < 2) ? sW + (size_t)l * 16384
                               : ((l == 2) ? mW : aW + (size_t)(l - 3) * 16384);
    Wbf[(size_t)l * 16384 + c * 128 + k] = f2bf(src[k * 128 + c]);
}

// ---------------- L0 propagation of raw x (2 channels) ----------------
__global__ void k_prop2(const float* __restrict__ x, float* __restrict__ P0,
                        const int* __restrict__ rowptr, const int2* __restrict__ csr,
                        const float* __restrict__ dinv) {
    int n = blockIdx.x * 256 + threadIdx.x;
    if (n >= NN) return;
    int b = blockIdx.y;
    const float* xb = x + (size_t)b * NN * 2;
    float d2 = dinv[n] * dinv[n];
    float a0 = d2 * xb[2 * n], a1 = d2 * xb[2 * n + 1];
    int beg = rowptr[n], end = rowptr[n + 1];
    for (int j = beg; j < end; j++) {
        int2 e2 = csr[j];
        int s = e2.x;
        float cf = __int_as_float(e2.y);
        a0 += cf * xb[2 * s];
        a1 += cf * xb[2 * s + 1];
    }
    float* Pb = P0 + (size_t)(n * BB + b) * 2;
    Pb[0] = a0;
    Pb[1] = a1;
}

// L0 matmul (K=2), writes chunked layout, fused BN partial stats pS[c][part].
__global__ void __launch_bounds__(256) k_mm2(const float* __restrict__ P0,
                                             ushort_t* __restrict__ A,
                                             const float* __restrict__ W,
                                             const float* __restrict__ bias,
                                             float* __restrict__ pS1, float* __restrict__ pS2) {
    __shared__ float L1[256][8], L2[256][8];
    int t = threadIdx.x;
    int cg = t & 15, c8 = cg * 8;
    float wv0[8], wv1[8], bv[8];
#pragma unroll
    for (int j = 0; j < 8; j++) {
        wv0[j] = W[c8 + j];
        wv1[j] = W[HH + c8 + j];
        bv[j] = bias[c8 + j];
    }
    float s1[8], s2[8];
#pragma unroll
    for (int j = 0; j < 8; j++) { s1[j] = 0.f; s2[j] = 0.f; }
    for (int idx = blockIdx.x * 256 + t; idx < RR * 16; idx += gridDim.x * 256) {
        int Rr = idx >> 4;
        int q = Rr / CROWS;
        int rr = Rr - q * CROWS;
        int n = rr >> 1;
        int b = q * 2 + (rr & 1);
        float p0 = P0[((size_t)n * BB + b) * 2], p1 = P0[((size_t)n * BB + b) * 2 + 1];
        short8 o;
#pragma unroll
        for (int j = 0; j < 8; j++) {
            float v = p0 * wv0[j] + p1 * wv1[j] + bv[j];
            s1[j] += v;
            s2[j] += v * v;
            o[j] = (short)f2bf(v);
        }
        *(short8*)(A + (size_t)Rr * HH + c8) = o;
    }
#pragma unroll
    for (int j = 0; j < 8; j++) { L1[t][j] = s1[j]; L2[t][j] = s2[j]; }
    __syncthreads();
    if (t < 16) {
#pragma unroll
        for (int g = 1; g < 16; g++)
#pragma unroll
            for (int j = 0; j < 8; j++) {
                s1[j] = (g == 1 ? L1[t][j] : s1[j]) + L1[t + 16 * g][j];
                s2[j] = (g == 1 ? L2[t][j] : s2[j]) + L2[t + 16 * g][j];
            }
#pragma unroll
        for (int j = 0; j < 8; j++) {
            pS1[(size_t)(t * 8 + j) * NPART0 + blockIdx.x] = s1[j];
            pS2[(size_t)(t * 8 + j) * NPART0 + blockIdx.x] = s2[j];
        }
    }
}

// ---------------- standalone gather: BN-affine+ReLU+propagate, wave-per-node ----------------
// chunked (2 batches = 4.6MB L2-resident, blockIdx&7 XCD-routed); 9-iteration chains;
// no LDS, no barriers; writes P (bf16) to global.
__global__ void __launch_bounds__(256) k_gather(const ushort_t* __restrict__ h,
                                                ushort_t* __restrict__ P,
                                                const int* __restrict__ rowptr,
                                                const int2* __restrict__ csr,
                                                const float* __restrict__ dinv,
                                                const float* __restrict__ scale,
                                                const float* __restrict__ shiftv, int shn) {
    int t = threadIdx.x;
    int q = blockIdx.x & 7;       // chunk -> XCD routing
    int ng4 = blockIdx.x >> 3;    // 0..2249
    int wv = t >> 6, l = t & 63;
    int n = ng4 * 4 + wv;         // wave's node (2250*4 = 9000 exact)
    int bi = l >> 5, c4 = (l & 31) * 4;
    const ushort_t* hb = h + (size_t)q * CROWS * HH;
    float sc[4], sh[4];
#pragma unroll
    for (int j = 0; j < 4; j++) {
        sc[j] = scale[c4 + j];
        sh[j] = shiftv[c4 + j];
    }
    int pn = n + shn;
    if (pn >= NN) pn -= NN;
    float d2 = dinv[n] * dinv[n];
    float acc[4];
    {
        short4v v = *(const short4v*)(hb + ((size_t)pn * 2 + bi) * HH + c4);
#pragma unroll
        for (int j = 0; j < 4; j++) {
            float f = bf2f((ushort_t)v[j]) * sc[j] + sh[j];
            acc[j] = d2 * fmaxf(f, 0.f);
        }
    }
    int beg = rowptr[n], end = rowptr[n + 1];
    for (int e = beg; e < end; e++) {
        int2 e2 = csr[e];
        int s = e2.x;
        float cf = __int_as_float(e2.y);
        int ps = s + shn;
        if (ps >= NN) ps -= NN;
        short4v v = *(const short4v*)(hb + ((size_t)ps * 2 + bi) * HH + c4);
#pragma unroll
        for (int j = 0; j < 4; j++) {
            float f = bf2f((ushort_t)v[j]) * sc[j] + sh[j];
            acc[j] += cf * fmaxf(f, 0.f);
        }
    }
    short4v o;
#pragma unroll
    for (int j = 0; j < 4; j++) o[j] = (short)f2bf(acc[j]);
    *(short4v*)(P + ((size_t)q * CROWS + (size_t)n * 2 + bi) * HH + c4) = o;
}

// ---------------- dense MFMA matmul: A = P*W + bias, fused BN partial stats ----------------
// 64-row tiles, A-frags direct from global P (no LDS staging); 2250 blocks exact.
__global__ void __launch_bounds__(256) k_mfma2(const ushort_t* __restrict__ P,
                                               ushort_t* __restrict__ A,
                                               const ushort_t* __restrict__ Wbf,
                                               const float* __restrict__ bias,
                                               float* __restrict__ pS1,
                                               float* __restrict__ pS2) {
    __shared__ float rb1[4][128], rb2[4][128];  // 4 KB stats reduction
    int t = threadIdx.x;
    int w = t >> 6, l = t & 63;
    int rw = w >> 1, cw = w & 1;  // 32-row half x 64-col half
    int lr = l & 31, hi = l >> 5;
    size_t rbase = (size_t)blockIdx.x * 64;
    const ushort_t* Pr0 = P + (rbase + rw * 32 + lr) * HH;
    const ushort_t* Wc0 = Wbf + (size_t)(cw * 64 + lr) * HH;
    const ushort_t* Wc1 = Wbf + (size_t)(cw * 64 + 32 + lr) * HH;
    float16v acc2[2];
#pragma unroll
    for (int ct = 0; ct < 2; ct++) acc2[ct] = (float16v)(0.0f);
#pragma unroll
    for (int ks = 0; ks < 8; ks++) {
        int koff = ks * 16 + hi * 8;
        short8 a0 = *(const short8*)(Pr0 + koff);
        short8 b0 = *(const short8*)(Wc0 + koff);
        short8 b1 = *(const short8*)(Wc1 + koff);
        acc2[0] = __builtin_amdgcn_mfma_f32_32x32x16_bf16(a0, b0, acc2[0], 0, 0, 0);
        acc2[1] = __builtin_amdgcn_mfma_f32_32x32x16_bf16(a0, b1, acc2[1], 0, 0, 0);
    }
    // epilogue: bias, stats, store bf16
    float bv[2] = {bias[cw * 64 + lr], bias[cw * 64 + 32 + lr]};
    float s1a[2] = {0.f, 0.f}, s2a[2] = {0.f, 0.f};
#pragma unroll
    for (int ct = 0; ct < 2; ct++) {
        int c = cw * 64 + ct * 32 + lr;
#pragma unroll
        for (int g = 0; g < 16; g++) {
            int row = rw * 32 + (g & 3) + 8 * (g >> 2) + 4 * hi;
            float v = acc2[ct][g] + bv[ct];
            s1a[ct] += v;
            s2a[ct] += v * v;
            A[(rbase + row) * HH + c] = f2bf(v);
        }
    }
    int slot = rw * 2 + hi;
#pragma unroll
    for (int ct = 0; ct < 2; ct++) {
        int cidx = cw * 64 + ct * 32 + lr;
        rb1[slot][cidx] = s1a[ct];
        rb2[slot][cidx] = s2a[ct];
    }
    __syncthreads();
    if (t < 128) {
        float a1 = rb1[0][t] + rb1[1][t] + rb1[2][t] + rb1[3][t];
        float a2 = rb2[0][t] + rb2[1][t] + rb2[2][t] + rb2[3][t];
        pS1[(size_t)t * NTILES + blockIdx.x] = a1;  // transposed: [channel][tile]
        pS2[(size_t)t * NTILES + blockIdx.x] = a2;
    }
}

// finalize BN affine from transposed partials: one block per channel, coalesced rows
__global__ void __launch_bounds__(256) k_bnfin(const float* __restrict__ pS1,
                                               const float* __restrict__ pS2, int npart,
                                               const float* __restrict__ g,
                                               const float* __restrict__ be,
                                               float* __restrict__ scale,
                                               float* __restrict__ shiftv) {
    __shared__ float R1[256], R2[256];
    int c = blockIdx.x;
    int t = threadIdx.x;
    const float* p1 = pS1 + (size_t)c * npart;
    const float* p2 = pS2 + (size_t)c * npart;
    float s1 = 0.f, s2 = 0.f;
    for (int i = t; i < npart; i += 256) {
        s1 += p1[i];
        s2 += p2[i];
    }
    R1[t] = s1;
    R2[t] = s2;
    __syncthreads();
    for (int d = 128; d > 0; d >>= 1) {
        if (t < d) {
            R1[t] += R1[t + d];
            R2[t] += R2[t + d];
        }
        __syncthreads();
    }
    if (t == 0) {
        float inv = 1.0f / (float)RR;
        float mu = R1[0] * inv;
        float var = R2[0] * inv - mu * mu;
        float sc = g[c] * rsqrtf(var + EPSB);
        scale[c] = sc;
        shiftv[c] = be[c] - mu * sc;
    }
}

// fused BN-affine + ReLU + mean-pool (per head), chunked layout reads
__global__ void __launch_bounds__(256) k_relu_pool(const ushort_t* __restrict__ A,
                                                   const float* __restrict__ scale,
                                                   const float* __restrict__ shiftv,
                                                   float* __restrict__ pooled) {
    __shared__ float L[256][8];
    int t = threadIdx.x;
    int b = blockIdx.y;
    int n0 = blockIdx.x * 250;
    int ng = t >> 4, c8 = (t & 15) * 8;
    float sc[8], sh[8];
#pragma unroll
    for (int j = 0; j < 8; j++) {
        sc[j] = scale[c8 + j];
        sh[j] = shiftv[c8 + j];
    }
    const ushort_t* Ab = A + ((size_t)(b >> 1) * CROWS + (b & 1)) * HH;
    float acc[8];
#pragma unroll
    for (int j = 0; j < 8; j++) acc[j] = 0.f;
    for (int n = n0 + ng; n < n0 + 250; n += 16) {
        short8 v = *(const short8*)(Ab + (size_t)n * 2 * HH + c8);
#pragma unroll
        for (int j = 0; j < 8; j++) {
            float f = bf2f((ushort_t)v[j]) * sc[j] + sh[j];
            acc[j] += fmaxf(f, 0.f);
        }
    }
#pragma unroll
    for (int j = 0; j < 8; j++) L[t][j] = acc[j];
    __syncthreads();
    if (ng == 0) {
#pragma unroll
        for (int g = 1; g < 16; g++)
#pragma unroll
            for (int j = 0; j < 8; j++) acc[j] += L[t + 16 * g][j];
#pragma unroll
        for (int j = 0; j < 8; j++) atomicAdd(&pooled[b * HH + t * 8 + j], acc[j]);
    }
}

// all 9 heads: linear + log_softmax
__global__ void __launch_bounds__(192) k_head_all(const float* __restrict__ pooled,
                                                  const float* __restrict__ main_Wf,
                                                  const float* __restrict__ main_bf,
                                                  const float* __restrict__ aux_Wf,
                                                  const float* __restrict__ aux_bf,
                                                  float* __restrict__ out) {
    int hd = blockIdx.x;
    const float* Wf = hd ? aux_Wf + (size_t)(hd - 1) * HH * NCLSS : main_Wf;
    const float* bf = hd ? aux_bf + (hd - 1) * NCLSS : main_bf;
    const float* pl = pooled + (size_t)hd * BB * HH;
    __shared__ float z[BB][NCLSS];
    __shared__ float lse[BB];
    int t = threadIdx.x;
    int b = t / NCLSS, j = t % NCLSS;
    if (t < BB * NCLSS) {
        float acc = bf[j];
        const float invn = 1.0f / NN;
        for (int c = 0; c < HH; c++) acc += pl[b * HH + c] * invn * Wf[c * NCLSS + j];
        z[b][j] = acc;
    }
    __syncthreads();
    if (t < BB) {
        float m = -1e30f;
        for (int j2 = 0; j2 < NCLSS; j2++) m = fmaxf(m, z[t][j2]);
        float s = 0.f;
        for (int j2 = 0; j2 < NCLSS; j2++) s += expf(z[t][j2] - m);
        lse[t] = m + logf(s);
    }
    __syncthreads();
    if (t < BB * NCLSS) {
        float* o = hd ? out + BB * NCLSS + ((size_t)b * 8 + (hd - 1)) * NCLSS + j
                      : out + b * NCLSS + j;
        *o = z[b][j] - lse[b];
    }
}

// ---------------- host ----------------

extern "C" void kernel_launch(void* const* d_in, const int* in_sizes, int n_in, void* d_out,
                              int out_size, void* d_ws, size_t ws_size, hipStream_t stream) {
    const float* x = (const float*)d_in[0];
    const int* ei = (const int*)d_in[1];
    const float* W_in = (const float*)d_in[2];
    const float* b_in = (const float*)d_in[3];
    const float* g_in = (const float*)d_in[4];
    const float* be_in = (const float*)d_in[5];
    const float* shared_W = (const float*)d_in[6];
    const float* shared_b = (const float*)d_in[7];
    const float* shared_g = (const float*)d_in[8];
    const float* shared_be = (const float*)d_in[9];
    const float* main_Wg = (const float*)d_in[10];
    const float* main_bg = (const float*)d_in[11];
    const float* main_g = (const float*)d_in[12];
    const float* main_be = (const float*)d_in[13];
    const float* main_Wf = (const float*)d_in[14];
    const float* main_bf = (const float*)d_in[15];
    const float* aux_Wg = (const float*)d_in[16];
    const float* aux_bg = (const float*)d_in[17];
    const float* aux_g = (const float*)d_in[18];
    const float* aux_be = (const float*)d_in[19];
    const float* aux_Wf = (const float*)d_in[20];
    const float* aux_bf = (const float*)d_in[21];
    float* out = (float*)d_out;

    char* w = (char*)d_ws;
    const size_t BIG = (size_t)RR * HH * 2;
    ushort_t* U = (ushort_t*)w;  w += BIG;
    ushort_t* V = (ushort_t*)w;  w += BIG;
    ushort_t* P = (ushort_t*)w;  w += BIG;
    float* P0 = (float*)w;       w += (size_t)RR * 2 * 4;
    ushort_t* Wbf = (ushort_t*)w; w += (size_t)11 * 16384 * 2;
    int2* csr = (int2*)w;        w += (size_t)EE * 8;
    int* counts = (int*)w;       w += NN * 4;
    int* cursor = (int*)w;       w += NN * 4;
    float* dinv = (float*)w;     w += NN * 4;
    int* rowptr = (int*)w;       w += 36016;
    float* pS1 = (float*)w;      w += (size_t)HH * NTILES * 4;
    float* pS2 = (float*)w;      w += (size_t)HH * NTILES * 4;
    float* pooled = (float*)w;   w += 9 * BB * HH * 4;
    float* tscale = (float*)w;   w += 512;
    float* tshift = (float*)w;   w += 512;
    float* hscale = (float*)w;   w += 512;
    float* hshift = (float*)w;   w += 512;

    hipMemsetAsync(counts, 0, 2 * NN * 4, stream);
    hipMemsetAsync(pooled, 0, 9 * BB * HH * 4, stream);

    k_count<<<(EE + 255) / 256, 256, 0, stream>>>(ei, counts);
    k_dinv<<<(NN + 255) / 256, 256, 0, stream>>>(counts, dinv);
    k_scan<<<1, 1024, 0, stream>>>(counts, rowptr);
    k_fill<<<(EE + 255) / 256, 256, 0, stream>>>(ei, rowptr, cursor, dinv, csr);
    k_wcvt<<<(11 * 16384 + 255) / 256, 256, 0, stream>>>(shared_W, main_Wg, aux_Wg, Wbf);

    // L0
    {
        dim3 g((NN + 255) / 256, BB);
        k_prop2<<<g, 256, 0, stream>>>(x, P0, rowptr, csr, dinv);
        k_mm2<<<NPART0, 256, 0, stream>>>(P0, U, W_in, b_in, pS1, pS2);
        k_bnfin<<<HH, 256, 0, stream>>>(pS1, pS2, NPART0, g_in, be_in, tscale, tshift);
    }

    // shared trunk layers (gather -> mfma -> bnfin)
    ushort_t* hcur = U;
    ushort_t* hnext = V;
    for (int l = 0; l < 2; l++) {
        k_gather<<<8 * 2250, 256, 0, stream>>>(hcur, P, rowptr, csr, dinv, tscale, tshift, 0);
        k_mfma2<<<NTILES, 256, 0, stream>>>(P, hnext, Wbf + (size_t)l * 16384,
                                            shared_b + l * HH, pS1, pS2);
        k_bnfin<<<HH, 256, 0, stream>>>(pS1, pS2, NTILES, shared_g + l * HH, shared_be + l * HH,
                                        tscale, tshift);
        ushort_t* tmp = hcur; hcur = hnext; hnext = tmp;
    }

    // heads
    for (int hd = 0; hd < 9; hd++) {
        int shift = hd * 1000;
        const ushort_t* Wg = Wbf + (size_t)(2 + hd) * 16384;
        const float* bg = (hd == 0) ? main_bg : aux_bg + (hd - 1) * HH;
        const float* gg = (hd == 0) ? main_g : aux_g + (hd - 1) * HH;
        const float* be = (hd == 0) ? main_be : aux_be + (hd - 1) * HH;

        k_gather<<<8 * 2250, 256, 0, stream>>>(hcur, P, rowptr, csr, dinv, tscale, tshift, shift);
        k_mfma2<<<NTILES, 256, 0, stream>>>(P, hnext, Wg, bg, pS1, pS2);
        k_bnfin<<<HH, 256, 0, stream>>>(pS1, pS2, NTILES, gg, be, hscale, hshift);
        dim3 gp(36, BB);
        k_relu_pool<<<gp, 256, 0, stream>>>(hnext, hscale, hshift, pooled + (size_t)hd * BB * HH);
    }
    k_head_all<<<9, 192, 0, stream>>>(pooled, main_Wf, main_bf, aux_Wf, aux_bf, out);
}

// Round 11
// 1350.870 us; speedup vs baseline: 1.1701x; 1.0210x over previous
//
#include <hip/hip_runtime.h>
#include <hip/hip_bf16.h>
#include <math.h>

#define BB 16
#define TT 360
#define VV 25
#define NN 9000
#define EE 72000
#define HH 128
#define RR (NN * BB)       // 144000 rows total
#define CROWS 18000        // rows per chunk (9000 nodes x 2 batches)
#define NTILES (RR / 64)   // 2250 tiles of 64 rows for k_mfma2 (exact)
#define NPART0 563         // partial-stats blocks for k_mm2 (L0)
#define NCLSS 12
#define EPSB 1e-5f

// chunked activation layout: row R(n,b) = (b>>1)*CROWS + n*2 + (b&1)

typedef _Float16 h4v __attribute__((ext_vector_type(4)));
typedef _Float16 h8v __attribute__((ext_vector_type(8)));
typedef float float16v __attribute__((ext_vector_type(16)));

// ---------------- graph preprocessing ----------------

__global__ void k_count(const int* __restrict__ ei, int* __restrict__ counts) {
    int e = blockIdx.x * 256 + threadIdx.x;
    if (e < EE) atomicAdd(&counts[ei[EE + e]], 1);
}

// dinv (f32) + packed half2 of dinv^2 (self-loop coef)
__global__ void k_dinv(const int* __restrict__ counts, float* __restrict__ dinv,
                       unsigned* __restrict__ d2p) {
    int n = blockIdx.x * 256 + threadIdx.x;
    if (n >= NN) return;
    float di = rsqrtf((float)(counts[n] + 1));
    dinv[n] = di;
    _Float16 d2 = (_Float16)(di * di);
    unsigned short u = __builtin_bit_cast(unsigned short, d2);
    d2p[n] = (unsigned)u | ((unsigned)u << 16);
}

__global__ void k_scan(const int* __restrict__ counts, int* __restrict__ rowptr) {
    __shared__ int part[1024];
    int t = threadIdx.x;
    int base = t * 9;
    int loc[9];
    int s = 0;
#pragma unroll
    for (int i = 0; i < 9; i++) {
        int idx = base + i;
        int v = (idx < NN) ? counts[idx] : 0;
        loc[i] = s;
        s += v;
    }
    part[t] = s;
    __syncthreads();
    for (int d = 1; d < 1024; d <<= 1) {
        int v = (t >= d) ? part[t - d] : 0;
        __syncthreads();
        part[t] += v;
        __syncthreads();
    }
    int excl = (t == 0) ? 0 : part[t - 1];
#pragma unroll
    for (int i = 0; i < 9; i++) {
        int idx = base + i;
        if (idx < NN) rowptr[idx] = excl + loc[i];
    }
    if (t == 1023) rowptr[NN] = part[1023];
}

// csr entry: {src, coef packed as half2(cf,cf)}
__global__ void k_fill(const int* __restrict__ ei, const int* __restrict__ rowptr,
                       int* __restrict__ cursor, const float* __restrict__ dinv,
                       int2* __restrict__ csr) {
    int e = blockIdx.x * 256 + threadIdx.x;
    if (e >= EE) return;
    int s = ei[e], d = ei[EE + e];
    int slot = rowptr[d] + atomicAdd(&cursor[d], 1);
    _Float16 cfh = (_Float16)(dinv[s] * dinv[d]);
    unsigned short u = __builtin_bit_cast(unsigned short, cfh);
    int2 e2;
    e2.x = s;
    e2.y = (int)((unsigned)u | ((unsigned)u << 16));
    csr[slot] = e2;
}

// pre-convert the 11 layer weight matrices to f16 W^T images: Wh[l][c*128+k]
__global__ void k_wcvt(const float* __restrict__ sW, const float* __restrict__ mW,
                       const float* __restrict__ aW, _Float16* __restrict__ Wh) {
    int idx = blockIdx.x * 256 + threadIdx.x;
    if (idx >= 11 * 16384) return;
    int l = idx >> 14, r = idx & 16383;
    int k = r >> 7, c = r & 127;
    const float* src = (l < 2) ? sW + (size_t)l * 16384
                               : ((l == 2) ? mW : aW + (size_t)(l - 3) * 16384);
    Wh[(size_t)l * 16384 + c * 128 + k] = (_Float16)src[k * 128 + c];
}

// ---------------- L0 propagation of raw x (2 channels, f32) ----------------
__global__ void k_prop2(const float* __restrict__ x, float* __restrict__ P0,
                        const int* __restrict__ rowptr, const int2* __restrict__ csr,
                        const float* __restrict__ dinv) {
    int n = blockIdx.x * 256 + threadIdx.x;
    if (n >= NN) return;
    int b = blockIdx.y;
    const float* xb = x + (size_t)b * NN * 2;
    float d2 = dinv[n] * dinv[n];
    float a0 = d2 * xb[2 * n], a1 = d2 * xb[2 * n + 1];
    int beg = rowptr[n], end = rowptr[n + 1];
    for (int j = beg; j < end; j++) {
        int2 e2 = csr[j];
        int s = e2.x;
        unsigned short u = (unsigned short)((unsigned)e2.y & 0xffffu);
        float cf = (float)__builtin_bit_cast(_Float16, u);
        a0 += cf * xb[2 * s];
        a1 += cf * xb[2 * s + 1];
    }
    float* Pb = P0 + (size_t)(n * BB + b) * 2;
    Pb[0] = a0;
    Pb[1] = a1;
}

// L0 matmul (K=2), writes chunked f16 layout, fused BN partial stats pS[c][part].
__global__ void __launch_bounds__(256) k_mm2(const float* __restrict__ P0,
                                             _Float16* __restrict__ A,
                                             const float* __restrict__ W,
                                             const float* __restrict__ bias,
                                             float* __restrict__ pS1, float* __restrict__ pS2) {
    __shared__ float L1[256][8], L2[256][8];
    int t = threadIdx.x;
    int cg = t & 15, c8 = cg * 8;
    float wv0[8], wv1[8], bv[8];
#pragma unroll
    for (int j = 0; j < 8; j++) {
        wv0[j] = W[c8 + j];
        wv1[j] = W[HH + c8 + j];
        bv[j] = bias[c8 + j];
    }
    float s1[8], s2[8];
#pragma unroll
    for (int j = 0; j < 8; j++) { s1[j] = 0.f; s2[j] = 0.f; }
    for (int idx = blockIdx.x * 256 + t; idx < RR * 16; idx += gridDim.x * 256) {
        int Rr = idx >> 4;
        int q = Rr / CROWS;
        int rr = Rr - q * CROWS;
        int n = rr >> 1;
        int b = q * 2 + (rr & 1);
        float p0 = P0[((size_t)n * BB + b) * 2], p1 = P0[((size_t)n * BB + b) * 2 + 1];
        h8v o;
#pragma unroll
        for (int j = 0; j < 8; j++) {
            float v = p0 * wv0[j] + p1 * wv1[j] + bv[j];
            s1[j] += v;
            s2[j] += v * v;
            o[j] = (_Float16)v;
        }
        *(h8v*)(A + (size_t)Rr * HH + c8) = o;
    }
#pragma unroll
    for (int j = 0; j < 8; j++) { L1[t][j] = s1[j]; L2[t][j] = s2[j]; }
    __syncthreads();
    if (t < 16) {
#pragma unroll
        for (int g = 1; g < 16; g++)
#pragma unroll
            for (int j = 0; j < 8; j++) {
                s1[j] = (g == 1 ? L1[t][j] : s1[j]) + L1[t + 16 * g][j];
                s2[j] = (g == 1 ? L2[t][j] : s2[j]) + L2[t + 16 * g][j];
            }
#pragma unroll
        for (int j = 0; j < 8; j++) {
            pS1[(size_t)(t * 8 + j) * NPART0 + blockIdx.x] = s1[j];
            pS2[(size_t)(t * 8 + j) * NPART0 + blockIdx.x] = s2[j];
        }
    }
}

// ---------------- activation pass: h' = relu(A*sc+sh), f16 -> f16 ----------------
__global__ void __launch_bounds__(256) k_act(const _Float16* __restrict__ A,
                                             _Float16* __restrict__ HP,
                                             const float* __restrict__ scale,
                                             const float* __restrict__ shiftv) {
    int i = blockIdx.x * 256 + threadIdx.x;  // over RR*16 groups of 8 channels
    int c8 = (i & 15) * 8;
    h8v v = *(const h8v*)(A + (size_t)i * 8);
    h8v o;
#pragma unroll
    for (int j = 0; j < 8; j++) {
        float f = (float)v[j] * scale[c8 + j] + shiftv[c8 + j];
        o[j] = (_Float16)fmaxf(f, 0.f);
    }
    *(h8v*)(HP + (size_t)i * 8) = o;
}

// ---------------- pure gather: P = A_hat * h' (packed f16 FMA) ----------------
// chunked (2 batches = 4.6MB L2-resident, blockIdx&7 XCD-routed); wave-per-node.
__global__ void __launch_bounds__(256) k_gather(const _Float16* __restrict__ h,
                                                _Float16* __restrict__ P,
                                                const int* __restrict__ rowptr,
                                                const int2* __restrict__ csr,
                                                const unsigned* __restrict__ d2p, int shn) {
    int t = threadIdx.x;
    int q = blockIdx.x & 7;     // chunk -> XCD routing
    int ng4 = blockIdx.x >> 3;  // 0..2249
    int wv = t >> 6, l = t & 63;
    int n = ng4 * 4 + wv;       // wave's node (2250*4 = 9000 exact)
    int bi = l >> 5, c4 = (l & 31) * 4;
    const _Float16* hb = h + (size_t)q * CROWS * HH + (size_t)bi * HH + c4;
    int pn = n + shn;
    if (pn >= NN) pn -= NN;
    h4v acc;
    {
        unsigned dp = d2p[n];
        uint2 dd = {dp, dp};
        h4v d4 = __builtin_bit_cast(h4v, dd);
        h4v v = *(const h4v*)(hb + (size_t)pn * 2 * HH);
        acc = v * d4;
    }
    int beg = rowptr[n], end = rowptr[n + 1];
    for (int e = beg; e < end; e++) {
        int2 e2 = csr[e];
        int s = e2.x;
        unsigned cp = (unsigned)e2.y;
        uint2 cc = {cp, cp};
        h4v cv = __builtin_bit_cast(h4v, cc);
        int ps = s + shn;
        if (ps >= NN) ps -= NN;
        h4v v = *(const h4v*)(hb + (size_t)ps * 2 * HH);
        acc += v * cv;  // v_pk_fma_f16 x2
    }
    *(h4v*)(P + ((size_t)q * CROWS + (size_t)n * 2 + bi) * HH + c4) = acc;
}

// ---------------- dense MFMA matmul (f16): A = P*W + bias, fused BN partial stats ----
__global__ void __launch_bounds__(256) k_mfma2(const _Float16* __restrict__ P,
                                               _Float16* __restrict__ A,
                                               const _Float16* __restrict__ Wh,
                                               const float* __restrict__ bias,
                                               float* __restrict__ pS1,
                                               float* __restrict__ pS2) {
    __shared__ float rb1[4][128], rb2[4][128];  // 4 KB stats reduction
    int t = threadIdx.x;
    int w = t >> 6, l = t & 63;
    int rw = w >> 1, cw = w & 1;  // 32-row half x 64-col half
    int lr = l & 31, hi = l >> 5;
    size_t rbase = (size_t)blockIdx.x * 64;
    const _Float16* Pr0 = P + (rbase + rw * 32 + lr) * HH;
    const _Float16* Wc0 = Wh + (size_t)(cw * 64 + lr) * HH;
    const _Float16* Wc1 = Wh + (size_t)(cw * 64 + 32 + lr) * HH;
    float16v acc2[2];
#pragma unroll
    for (int ct = 0; ct < 2; ct++) acc2[ct] = (float16v)(0.0f);
#pragma unroll
    for (int ks = 0; ks < 8; ks++) {
        int koff = ks * 16 + hi * 8;
        h8v a0 = *(const h8v*)(Pr0 + koff);
        h8v b0 = *(const h8v*)(Wc0 + koff);
        h8v b1 = *(const h8v*)(Wc1 + koff);
        acc2[0] = __builtin_amdgcn_mfma_f32_32x32x16_f16(a0, b0, acc2[0], 0, 0, 0);
        acc2[1] = __builtin_amdgcn_mfma_f32_32x32x16_f16(a0, b1, acc2[1], 0, 0, 0);
    }
    // epilogue: bias, stats, store f16
    float bv[2] = {bias[cw * 64 + lr], bias[cw * 64 + 32 + lr]};
    float s1a[2] = {0.f, 0.f}, s2a[2] = {0.f, 0.f};
#pragma unroll
    for (int ct = 0; ct < 2; ct++) {
        int c = cw * 64 + ct * 32 + lr;
#pragma unroll
        for (int g = 0; g < 16; g++) {
            int row = rw * 32 + (g & 3) + 8 * (g >> 2) + 4 * hi;
            float v = acc2[ct][g] + bv[ct];
            s1a[ct] += v;
            s2a[ct] += v * v;
            A[(rbase + row) * HH + c] = (_Float16)v;
        }
    }
    int slot = rw * 2 + hi;
#pragma unroll
    for (int ct = 0; ct < 2; ct++) {
        int cidx = cw * 64 + ct * 32 + lr;
        rb1[slot][cidx] = s1a[ct];
        rb2[slot][cidx] = s2a[ct];
    }
    __syncthreads();
    if (t < 128) {
        float a1 = rb1[0][t] + rb1[1][t] + rb1[2][t] + rb1[3][t];
        float a2 = rb2[0][t] + rb2[1][t] + rb2[2][t] + rb2[3][t];
        pS1[(size_t)t * NTILES + blockIdx.x] = a1;  // transposed: [channel][tile]
        pS2[(size_t)t * NTILES + blockIdx.x] = a2;
    }
}

// finalize BN affine from transposed partials: one block per channel, coalesced rows
__global__ void __launch_bounds__(256) k_bnfin(const float* __restrict__ pS1,
                                               const float* __restrict__ pS2, int npart,
                                               const float* __restrict__ g,
                                               const float* __restrict__ be,
                                               float* __restrict__ scale,
                                               float* __restrict__ shiftv) {
    __shared__ float R1[256], R2[256];
    int c = blockIdx.x;
    int t = threadIdx.x;
    const float* p1 = pS1 + (size_t)c * npart;
    const float* p2 = pS2 + (size_t)c * npart;
    float s1 = 0.f, s2 = 0.f;
    for (int i = t; i < npart; i += 256) {
        s1 += p1[i];
        s2 += p2[i];
    }
    R1[t] = s1;
    R2[t] = s2;
    __syncthreads();
    for (int d = 128; d > 0; d >>= 1) {
        if (t < d) {
            R1[t] += R1[t + d];
            R2[t] += R2[t + d];
        }
        __syncthreads();
    }
    if (t == 0) {
        float inv = 1.0f / (float)RR;
        float mu = R1[0] * inv;
        float var = R2[0] * inv - mu * mu;
        float sc = g[c] * rsqrtf(var + EPSB);
        scale[c] = sc;
        shiftv[c] = be[c] - mu * sc;
    }
}

// fused BN-affine + ReLU + mean-pool (per head), chunked f16 reads
__global__ void __launch_bounds__(256) k_relu_pool(const _Float16* __restrict__ A,
                                                   const float* __restrict__ scale,
                                                   const float* __restrict__ shiftv,
                                                   float* __restrict__ pooled) {
    __shared__ float L[256][8];
    int t = threadIdx.x;
    int b = blockIdx.y;
    int n0 = blockIdx.x * 250;
    int ng = t >> 4, c8 = (t & 15) * 8;
    float sc[8], sh[8];
#pragma unroll
    for (int j = 0; j < 8; j++) {
        sc[j] = scale[c8 + j];
        sh[j] = shiftv[c8 + j];
    }
    const _Float16* Ab = A + ((size_t)(b >> 1) * CROWS + (b & 1)) * HH;
    float acc[8];
#pragma unroll
    for (int j = 0; j < 8; j++) acc[j] = 0.f;
    for (int n = n0 + ng; n < n0 + 250; n += 16) {
        h8v v = *(const h8v*)(Ab + (size_t)n * 2 * HH + c8);
#pragma unroll
        for (int j = 0; j < 8; j++) {
            float f = (float)v[j] * sc[j] + sh[j];
            acc[j] += fmaxf(f, 0.f);
        }
    }
#pragma unroll
    for (int j = 0; j < 8; j++) L[t][j] = acc[j];
    __syncthreads();
    if (ng == 0) {
#pragma unroll
        for (int g = 1; g < 16; g++)
#pragma unroll
            for (int j = 0; j < 8; j++) acc[j] += L[t + 16 * g][j];
#pragma unroll
        for (int j = 0; j < 8; j++) atomicAdd(&pooled[b * HH + t * 8 + j], acc[j]);
    }
}

// all 9 heads: linear + log_softmax
__global__ void __launch_bounds__(192) k_head_all(const float* __restrict__ pooled,
                                                  const float* __restrict__ main_Wf,
                                                  const float* __restrict__ main_bf,
                                                  const float* __restrict__ aux_Wf,
                                                  const float* __restrict__ aux_bf,
                                                  float* __restrict__ out) {
    int hd = blockIdx.x;
    const float* Wf = hd ? aux_Wf + (size_t)(hd - 1) * HH * NCLSS : main_Wf;
    const float* bf = hd ? aux_bf + (hd - 1) * NCLSS : main_bf;
    const float* pl = pooled + (size_t)hd * BB * HH;
    __shared__ float z[BB][NCLSS];
    __shared__ float lse[BB];
    int t = threadIdx.x;
    int b = t / NCLSS, j = t % NCLSS;
    if (t < BB * NCLSS) {
        float acc = bf[j];
        const float invn = 1.0f / NN;
        for (int c = 0; c < HH; c++) acc += pl[b * HH + c] * invn * Wf[c * NCLSS + j];
        z[b][j] = acc;
    }
    __syncthreads();
    if (t < BB) {
        float m = -1e30f;
        for (int j2 = 0; j2 < NCLSS; j2++) m = fmaxf(m, z[t][j2]);
        float s = 0.f;
        for (int j2 = 0; j2 < NCLSS; j2++) s += expf(z[t][j2] - m);
        lse[t] = m + logf(s);
    }
    __syncthreads();
    if (t < BB * NCLSS) {
        float* o = hd ? out + BB * NCLSS + ((size_t)b * 8 + (hd - 1)) * NCLSS + j
                      : out + b * NCLSS + j;
        *o = z[b][j] - lse[b];
    }
}

// ---------------- host ----------------

extern "C" void kernel_launch(void* const* d_in, const int* in_sizes, int n_in, void* d_out,
                              int out_size, void* d_ws, size_t ws_size, hipStream_t stream) {
    const float* x = (const float*)d_in[0];
    const int* ei = (const int*)d_in[1];
    const float* W_in = (const float*)d_in[2];
    const float* b_in = (const float*)d_in[3];
    const float* g_in = (const float*)d_in[4];
    const float* be_in = (const float*)d_in[5];
    const float* shared_W = (const float*)d_in[6];
    const float* shared_b = (const float*)d_in[7];
    const float* shared_g = (const float*)d_in[8];
    const float* shared_be = (const float*)d_in[9];
    const float* main_Wg = (const float*)d_in[10];
    const float* main_bg = (const float*)d_in[11];
    const float* main_g = (const float*)d_in[12];
    const float* main_be = (const float*)d_in[13];
    const float* main_Wf = (const float*)d_in[14];
    const float* main_bf = (const float*)d_in[15];
    const float* aux_Wg = (const float*)d_in[16];
    const float* aux_bg = (const float*)d_in[17];
    const float* aux_g = (const float*)d_in[18];
    const float* aux_be = (const float*)d_in[19];
    const float* aux_Wf = (const float*)d_in[20];
    const float* aux_bf = (const float*)d_in[21];
    float* out = (float*)d_out;

    char* w = (char*)d_ws;
    const size_t BIG = (size_t)RR * HH * 2;
    _Float16* U = (_Float16*)w;  w += BIG;
    _Float16* V = (_Float16*)w;  w += BIG;
    _Float16* P = (_Float16*)w;  w += BIG;
    _Float16* HP = (_Float16*)w; w += BIG;
    float* P0 = (float*)w;       w += (size_t)RR * 2 * 4;
    _Float16* Wh = (_Float16*)w; w += (size_t)11 * 16384 * 2;
    int2* csr = (int2*)w;        w += (size_t)EE * 8;
    int* counts = (int*)w;       w += NN * 4;
    int* cursor = (int*)w;       w += NN * 4;
    float* dinv = (float*)w;     w += NN * 4;
    unsigned* d2p = (unsigned*)w; w += NN * 4;
    int* rowptr = (int*)w;       w += 36016;
    float* pS1 = (float*)w;      w += (size_t)HH * NTILES * 4;
    float* pS2 = (float*)w;      w += (size_t)HH * NTILES * 4;
    float* pooled = (float*)w;   w += 9 * BB * HH * 4;
    float* tscale = (float*)w;   w += 512;
    float* tshift = (float*)w;   w += 512;
    float* hscale = (float*)w;   w += 512;
    float* hshift = (float*)w;   w += 512;

    hipMemsetAsync(counts, 0, 2 * NN * 4, stream);
    hipMemsetAsync(pooled, 0, 9 * BB * HH * 4, stream);

    k_count<<<(EE + 255) / 256, 256, 0, stream>>>(ei, counts);
    k_dinv<<<(NN + 255) / 256, 256, 0, stream>>>(counts, dinv, d2p);
    k_scan<<<1, 1024, 0, stream>>>(counts, rowptr);
    k_fill<<<(EE + 255) / 256, 256, 0, stream>>>(ei, rowptr, cursor, dinv, csr);
    k_wcvt<<<(11 * 16384 + 255) / 256, 256, 0, stream>>>(shared_W, main_Wg, aux_Wg, Wh);

    // L0
    {
        dim3 g((NN + 255) / 256, BB);
        k_prop2<<<g, 256, 0, stream>>>(x, P0, rowptr, csr, dinv);
        k_mm2<<<NPART0, 256, 0, stream>>>(P0, U, W_in, b_in, pS1, pS2);
        k_bnfin<<<HH, 256, 0, stream>>>(pS1, pS2, NPART0, g_in, be_in, tscale, tshift);
    }

    // shared trunk layers: act -> gather -> mfma -> bnfin
    _Float16* hcur = U;
    _Float16* hnext = V;
    for (int l = 0; l < 2; l++) {
        k_act<<<RR * 16 / 256, 256, 0, stream>>>(hcur, HP, tscale, tshift);
        k_gather<<<8 * 2250, 256, 0, stream>>>(HP, P, rowptr, csr, d2p, 0);
        k_mfma2<<<NTILES, 256, 0, stream>>>(P, hnext, Wh + (size_t)l * 16384,
                                            shared_b + l * HH, pS1, pS2);
        k_bnfin<<<HH, 256, 0, stream>>>(pS1, pS2, NTILES, shared_g + l * HH, shared_be + l * HH,
                                        tscale, tshift);
        _Float16* tmp = hcur; hcur = hnext; hnext = tmp;
    }

    // activate trunk output once; all 9 heads share it
    k_act<<<RR * 16 / 256, 256, 0, stream>>>(hcur, HP, tscale, tshift);

    // heads
    for (int hd = 0; hd < 9; hd++) {
        int shift = hd * 1000;
        const _Float16* Wg = Wh + (size_t)(2 + hd) * 16384;
        const float* bg = (hd == 0) ? main_bg : aux_bg + (hd - 1) * HH;
        const float* gg = (hd == 0) ? main_g : aux_g + (hd - 1) * HH;
        const float* be = (hd == 0) ? main_be : aux_be + (hd - 1) * HH;

        k_gather<<<8 * 2250, 256, 0, stream>>>(HP, P, rowptr, csr, d2p, shift);
        k_mfma2<<<NTILES, 256, 0, stream>>>(P, hnext, Wg, bg, pS1, pS2);
        k_bnfin<<<HH, 256, 0, stream>>>(pS1, pS2, NTILES, gg, be, hscale, hshift);
        dim3 gp(36, BB);
        k_relu_pool<<<gp, 256, 0, stream>>>(hnext, hscale, hshift, pooled + (size_t)hd * BB * HH);
    }
    k_head_all<<<9, 192, 0, stream>>>(pooled, main_Wf, main_bf, aux_Wf, aux_bf, out);
}

// Round 12
// 1119.411 us; speedup vs baseline: 1.4121x; 1.2068x over previous
//
#include <hip/hip_runtime.h>
#include <hip/hip_bf16.h>
#include <math.h>

#define BB 16
#define TT 360
#define VV 25
#define NN 9000
#define EE 72000
#define HH 128
#define RR (NN * BB)       // 144000 rows total
#define CROWS 18000        // rows per chunk (9000 nodes x 2 batches)
#define NTILES (RR / 64)   // 2250 tiles of 64 rows for k_mfma2 (exact)
#define NPART0 563         // partial-stats blocks for k_mm2 (L0)
#define NCLSS 12
#define EPSB 1e-5f

// chunked activation layout: row R(n,b) = (b>>1)*CROWS + n*2 + (b&1)

typedef _Float16 h4v __attribute__((ext_vector_type(4)));
typedef _Float16 h8v __attribute__((ext_vector_type(8)));
typedef float float16v __attribute__((ext_vector_type(16)));

__device__ __forceinline__ h4v cf4(unsigned packed) {
    uint2 cc = {packed, packed};
    return __builtin_bit_cast(h4v, cc);
}

// ---------------- graph preprocessing ----------------

__global__ void k_count(const int* __restrict__ ei, int* __restrict__ counts) {
    int e = blockIdx.x * 256 + threadIdx.x;
    if (e < EE) atomicAdd(&counts[ei[EE + e]], 1);
}

// dinv (f32) + packed half2 of dinv^2 (self-loop coef)
__global__ void k_dinv(const int* __restrict__ counts, float* __restrict__ dinv,
                       unsigned* __restrict__ d2p) {
    int n = blockIdx.x * 256 + threadIdx.x;
    if (n >= NN) return;
    float di = rsqrtf((float)(counts[n] + 1));
    dinv[n] = di;
    _Float16 d2 = (_Float16)(di * di);
    unsigned short u = __builtin_bit_cast(unsigned short, d2);
    d2p[n] = (unsigned)u | ((unsigned)u << 16);
}

// exclusive prefix over padded degrees deg4 = (deg+3)&~3
__global__ void k_scan(const int* __restrict__ counts, int* __restrict__ rowptr4) {
    __shared__ int part[1024];
    int t = threadIdx.x;
    int base = t * 9;
    int loc[9];
    int s = 0;
#pragma unroll
    for (int i = 0; i < 9; i++) {
        int idx = base + i;
        int v = (idx < NN) ? ((counts[idx] + 3) & ~3) : 0;
        loc[i] = s;
        s += v;
    }
    part[t] = s;
    __syncthreads();
    for (int d = 1; d < 1024; d <<= 1) {
        int v = (t >= d) ? part[t - d] : 0;
        __syncthreads();
        part[t] += v;
        __syncthreads();
    }
    int excl = (t == 0) ? 0 : part[t - 1];
#pragma unroll
    for (int i = 0; i < 9; i++) {
        int idx = base + i;
        if (idx < NN) rowptr4[idx] = excl + loc[i];
    }
    if (t == 1023) rowptr4[NN] = part[1023];
}

// csr entry: {src, coef packed as half2(cf,cf)}
__global__ void k_fill(const int* __restrict__ ei, const int* __restrict__ rowptr4,
                       int* __restrict__ cursor, const float* __restrict__ dinv,
                       int2* __restrict__ csr) {
    int e = blockIdx.x * 256 + threadIdx.x;
    if (e >= EE) return;
    int s = ei[e], d = ei[EE + e];
    int slot = rowptr4[d] + atomicAdd(&cursor[d], 1);
    _Float16 cfh = (_Float16)(dinv[s] * dinv[d]);
    unsigned short u = __builtin_bit_cast(unsigned short, cfh);
    int2 e2;
    e2.x = s;
    e2.y = (int)((unsigned)u | ((unsigned)u << 16));
    csr[slot] = e2;
}

// fill pad slots with {n, 0} (self row, zero coef)
__global__ void k_pad(const int* __restrict__ rowptr4, const int* __restrict__ cursor,
                      int2* __restrict__ csr) {
    int n = blockIdx.x * 256 + threadIdx.x;
    if (n >= NN) return;
    int beg = rowptr4[n] + cursor[n];
    int end = rowptr4[n + 1];
    int2 z;
    z.x = n;
    z.y = 0;
    for (int e = beg; e < end; e++) csr[e] = z;
}

// pre-convert the 11 layer weight matrices to f16 W^T images: Wh[l][c*128+k]
__global__ void k_wcvt(const float* __restrict__ sW, const float* __restrict__ mW,
                       const float* __restrict__ aW, _Float16* __restrict__ Wh) {
    int idx = blockIdx.x * 256 + threadIdx.x;
    if (idx >= 11 * 16384) return;
    int l = idx >> 14, r = idx & 16383;
    int k = r >> 7, c = r & 127;
    const float* src = (l < 2) ? sW + (size_t)l * 16384
                               : ((l == 2) ? mW : aW + (size_t)(l - 3) * 16384);
    Wh[(size_t)l * 16384 + c * 128 + k] = (_Float16)src[k * 128 + c];
}

// ---------------- L0 propagation of raw x (2 channels, f32) ----------------
__global__ void k_prop2(const float* __restrict__ x, float* __restrict__ P0,
                        const int* __restrict__ rowptr4, const int2* __restrict__ csr,
                        const float* __restrict__ dinv) {
    int n = blockIdx.x * 256 + threadIdx.x;
    if (n >= NN) return;
    int b = blockIdx.y;
    const float* xb = x + (size_t)b * NN * 2;
    float d2 = dinv[n] * dinv[n];
    float a0 = d2 * xb[2 * n], a1 = d2 * xb[2 * n + 1];
    int beg = rowptr4[n], end = rowptr4[n + 1];
    for (int j = beg; j < end; j++) {
        int2 e2 = csr[j];
        int s = e2.x;
        unsigned short u = (unsigned short)((unsigned)e2.y & 0xffffu);
        float cf = (float)__builtin_bit_cast(_Float16, u);
        a0 += cf * xb[2 * s];
        a1 += cf * xb[2 * s + 1];
    }
    float* Pb = P0 + (size_t)(n * BB + b) * 2;
    Pb[0] = a0;
    Pb[1] = a1;
}

// L0 matmul (K=2), writes chunked f16 layout, fused BN partial stats pS[c][part].
__global__ void __launch_bounds__(256) k_mm2(const float* __restrict__ P0,
                                             _Float16* __restrict__ A,
                                             const float* __restrict__ W,
                                             const float* __restrict__ bias,
                                             float* __restrict__ pS1, float* __restrict__ pS2) {
    __shared__ float L1[256][8], L2[256][8];
    int t = threadIdx.x;
    int cg = t & 15, c8 = cg * 8;
    float wv0[8], wv1[8], bv[8];
#pragma unroll
    for (int j = 0; j < 8; j++) {
        wv0[j] = W[c8 + j];
        wv1[j] = W[HH + c8 + j];
        bv[j] = bias[c8 + j];
    }
    float s1[8], s2[8];
#pragma unroll
    for (int j = 0; j < 8; j++) { s1[j] = 0.f; s2[j] = 0.f; }
    for (int idx = blockIdx.x * 256 + t; idx < RR * 16; idx += gridDim.x * 256) {
        int Rr = idx >> 4;
        int q = Rr / CROWS;
        int rr = Rr - q * CROWS;
        int n = rr >> 1;
        int b = q * 2 + (rr & 1);
        float p0 = P0[((size_t)n * BB + b) * 2], p1 = P0[((size_t)n * BB + b) * 2 + 1];
        h8v o;
#pragma unroll
        for (int j = 0; j < 8; j++) {
            float v = p0 * wv0[j] + p1 * wv1[j] + bv[j];
            s1[j] += v;
            s2[j] += v * v;
            o[j] = (_Float16)v;
        }
        *(h8v*)(A + (size_t)Rr * HH + c8) = o;
    }
#pragma unroll
    for (int j = 0; j < 8; j++) { L1[t][j] = s1[j]; L2[t][j] = s2[j]; }
    __syncthreads();
    if (t < 16) {
#pragma unroll
        for (int g = 1; g < 16; g++)
#pragma unroll
            for (int j = 0; j < 8; j++) {
                s1[j] = (g == 1 ? L1[t][j] : s1[j]) + L1[t + 16 * g][j];
                s2[j] = (g == 1 ? L2[t][j] : s2[j]) + L2[t + 16 * g][j];
            }
#pragma unroll
        for (int j = 0; j < 8; j++) {
            pS1[(size_t)(t * 8 + j) * NPART0 + blockIdx.x] = s1[j];
            pS2[(size_t)(t * 8 + j) * NPART0 + blockIdx.x] = s2[j];
        }
    }
}

// ---------------- activation pass: h' = relu(A*sc+sh), f16 -> f16 ----------------
__global__ void __launch_bounds__(256) k_act(const _Float16* __restrict__ A,
                                             _Float16* __restrict__ HP,
                                             const float* __restrict__ scale,
                                             const float* __restrict__ shiftv) {
    int i = blockIdx.x * 256 + threadIdx.x;  // over RR*16 groups of 8 channels
    int c8 = (i & 15) * 8;
    h8v v = *(const h8v*)(A + (size_t)i * 8);
    h8v o;
#pragma unroll
    for (int j = 0; j < 8; j++) {
        float f = (float)v[j] * scale[c8 + j] + shiftv[c8 + j];
        o[j] = (_Float16)fmaxf(f, 0.f);
    }
    *(h8v*)(HP + (size_t)i * 8) = o;
}

// ---------------- pure gather: P = A_hat * h', 4 edges/iter (4-deep MLP) ----------------
// chunked (2 batches = 4.6MB L2-resident, blockIdx&7 XCD-routed); wave-per-node.
__global__ void __launch_bounds__(256) k_gather(const _Float16* __restrict__ h,
                                                _Float16* __restrict__ P,
                                                const int* __restrict__ rowptr4,
                                                const int2* __restrict__ csr,
                                                const unsigned* __restrict__ d2p, int shn) {
    int t = threadIdx.x;
    int q = blockIdx.x & 7;     // chunk -> XCD routing
    int ng4 = blockIdx.x >> 3;  // 0..2249
    int wv = t >> 6, l = t & 63;
    int n = ng4 * 4 + wv;       // wave's node (2250*4 = 9000 exact)
    int bi = l >> 5, c4 = (l & 31) * 4;
    const _Float16* hb = h + (size_t)q * CROWS * HH + (size_t)bi * HH + c4;
    int pn = n + shn;
    if (pn >= NN) pn -= NN;
    h4v acc;
    {
        h4v v = *(const h4v*)(hb + (size_t)pn * 2 * HH);
        acc = v * cf4(d2p[n]);
    }
    int beg = rowptr4[n], end = rowptr4[n + 1];  // multiples of 4, 32B-aligned segs
    for (int e = beg; e < end; e += 4) {
        int4 q0 = *(const int4*)(csr + e);      // entries e, e+1
        int4 q1 = *(const int4*)(csr + e + 2);  // entries e+2, e+3
        int s0 = q0.x + shn; if (s0 >= NN) s0 -= NN;
        int s1 = q0.z + shn; if (s1 >= NN) s1 -= NN;
        int s2 = q1.x + shn; if (s2 >= NN) s2 -= NN;
        int s3 = q1.z + shn; if (s3 >= NN) s3 -= NN;
        h4v v0 = *(const h4v*)(hb + (size_t)s0 * 2 * HH);  // 4 independent loads
        h4v v1 = *(const h4v*)(hb + (size_t)s1 * 2 * HH);
        h4v v2 = *(const h4v*)(hb + (size_t)s2 * 2 * HH);
        h4v v3 = *(const h4v*)(hb + (size_t)s3 * 2 * HH);
        acc += v0 * cf4((unsigned)q0.y);
        acc += v1 * cf4((unsigned)q0.w);
        acc += v2 * cf4((unsigned)q1.y);
        acc += v3 * cf4((unsigned)q1.w);
    }
    *(h4v*)(P + ((size_t)q * CROWS + (size_t)n * 2 + bi) * HH + c4) = acc;
}

// ---------------- dense MFMA matmul (f16): A = P*W + bias, fused BN partial stats ----
__global__ void __launch_bounds__(256) k_mfma2(const _Float16* __restrict__ P,
                                               _Float16* __restrict__ A,
                                               const _Float16* __restrict__ Wh,
                                               const float* __restrict__ bias,
                                               float* __restrict__ pS1,
                                               float* __restrict__ pS2) {
    __shared__ float rb1[4][128], rb2[4][128];  // 4 KB stats reduction
    int t = threadIdx.x;
    int w = t >> 6, l = t & 63;
    int rw = w >> 1, cw = w & 1;  // 32-row half x 64-col half
    int lr = l & 31, hi = l >> 5;
    size_t rbase = (size_t)blockIdx.x * 64;
    const _Float16* Pr0 = P + (rbase + rw * 32 + lr) * HH;
    const _Float16* Wc0 = Wh + (size_t)(cw * 64 + lr) * HH;
    const _Float16* Wc1 = Wh + (size_t)(cw * 64 + 32 + lr) * HH;
    float16v acc2[2];
#pragma unroll
    for (int ct = 0; ct < 2; ct++) acc2[ct] = (float16v)(0.0f);
#pragma unroll
    for (int ks = 0; ks < 8; ks++) {
        int koff = ks * 16 + hi * 8;
        h8v a0 = *(const h8v*)(Pr0 + koff);
        h8v b0 = *(const h8v*)(Wc0 + koff);
        h8v b1 = *(const h8v*)(Wc1 + koff);
        acc2[0] = __builtin_amdgcn_mfma_f32_32x32x16_f16(a0, b0, acc2[0], 0, 0, 0);
        acc2[1] = __builtin_amdgcn_mfma_f32_32x32x16_f16(a0, b1, acc2[1], 0, 0, 0);
    }
    // epilogue: bias, stats, store f16
    float bv[2] = {bias[cw * 64 + lr], bias[cw * 64 + 32 + lr]};
    float s1a[2] = {0.f, 0.f}, s2a[2] = {0.f, 0.f};
#pragma unroll
    for (int ct = 0; ct < 2; ct++) {
        int c = cw * 64 + ct * 32 + lr;
#pragma unroll
        for (int g = 0; g < 16; g++) {
            int row = rw * 32 + (g & 3) + 8 * (g >> 2) + 4 * hi;
            float v = acc2[ct][g] + bv[ct];
            s1a[ct] += v;
            s2a[ct] += v * v;
            A[(rbase + row) * HH + c] = (_Float16)v;
        }
    }
    int slot = rw * 2 + hi;
#pragma unroll
    for (int ct = 0; ct < 2; ct++) {
        int cidx = cw * 64 + ct * 32 + lr;
        rb1[slot][cidx] = s1a[ct];
        rb2[slot][cidx] = s2a[ct];
    }
    __syncthreads();
    if (t < 128) {
        float a1 = rb1[0][t] + rb1[1][t] + rb1[2][t] + rb1[3][t];
        float a2 = rb2[0][t] + rb2[1][t] + rb2[2][t] + rb2[3][t];
        pS1[(size_t)t * NTILES + blockIdx.x] = a1;  // transposed: [channel][tile]
        pS2[(size_t)t * NTILES + blockIdx.x] = a2;
    }
}

// finalize BN affine from transposed partials: one block per channel, coalesced rows
__global__ void __launch_bounds__(256) k_bnfin(const float* __restrict__ pS1,
                                               const float* __restrict__ pS2, int npart,
                                               const float* __restrict__ g,
                                               const float* __restrict__ be,
                                               float* __restrict__ scale,
                                               float* __restrict__ shiftv) {
    __shared__ float R1[256], R2[256];
    int c = blockIdx.x;
    int t = threadIdx.x;
    const float* p1 = pS1 + (size_t)c * npart;
    const float* p2 = pS2 + (size_t)c * npart;
    float s1 = 0.f, s2 = 0.f;
    for (int i = t; i < npart; i += 256) {
        s1 += p1[i];
        s2 += p2[i];
    }
    R1[t] = s1;
    R2[t] = s2;
    __syncthreads();
    for (int d = 128; d > 0; d >>= 1) {
        if (t < d) {
            R1[t] += R1[t + d];
            R2[t] += R2[t + d];
        }
        __syncthreads();
    }
    if (t == 0) {
        float inv = 1.0f / (float)RR;
        float mu = R1[0] * inv;
        float var = R2[0] * inv - mu * mu;
        float sc = g[c] * rsqrtf(var + EPSB);
        scale[c] = sc;
        shiftv[c] = be[c] - mu * sc;
    }
}

// fused BN-affine + ReLU + mean-pool (per head), chunked f16 reads
__global__ void __launch_bounds__(256) k_relu_pool(const _Float16* __restrict__ A,
                                                   const float* __restrict__ scale,
                                                   const float* __restrict__ shiftv,
                                                   float* __restrict__ pooled) {
    __shared__ float L[256][8];
    int t = threadIdx.x;
    int b = blockIdx.y;
    int n0 = blockIdx.x * 250;
    int ng = t >> 4, c8 = (t & 15) * 8;
    float sc[8], sh[8];
#pragma unroll
    for (int j = 0; j < 8; j++) {
        sc[j] = scale[c8 + j];
        sh[j] = shiftv[c8 + j];
    }
    const _Float16* Ab = A + ((size_t)(b >> 1) * CROWS + (b & 1)) * HH;
    float acc[8];
#pragma unroll
    for (int j = 0; j < 8; j++) acc[j] = 0.f;
    for (int n = n0 + ng; n < n0 + 250; n += 16) {
        h8v v = *(const h8v*)(Ab + (size_t)n * 2 * HH + c8);
#pragma unroll
        for (int j = 0; j < 8; j++) {
            float f = (float)v[j] * sc[j] + sh[j];
            acc[j] += fmaxf(f, 0.f);
        }
    }
#pragma unroll
    for (int j = 0; j < 8; j++) L[t][j] = acc[j];
    __syncthreads();
    if (ng == 0) {
#pragma unroll
        for (int g = 1; g < 16; g++)
#pragma unroll
            for (int j = 0; j < 8; j++) acc[j] += L[t + 16 * g][j];
#pragma unroll
        for (int j = 0; j < 8; j++) atomicAdd(&pooled[b * HH + t * 8 + j], acc[j]);
    }
}

// all 9 heads: linear + log_softmax
__global__ void __launch_bounds__(192) k_head_all(const float* __restrict__ pooled,
                                                  const float* __restrict__ main_Wf,
                                                  const float* __restrict__ main_bf,
                                                  const float* __restrict__ aux_Wf,
                                                  const float* __restrict__ aux_bf,
                                                  float* __restrict__ out) {
    int hd = blockIdx.x;
    const float* Wf = hd ? aux_Wf + (size_t)(hd - 1) * HH * NCLSS : main_Wf;
    const float* bf = hd ? aux_bf + (hd - 1) * NCLSS : main_bf;
    const float* pl = pooled + (size_t)hd * BB * HH;
    __shared__ float z[BB][NCLSS];
    __shared__ float lse[BB];
    int t = threadIdx.x;
    int b = t / NCLSS, j = t % NCLSS;
    if (t < BB * NCLSS) {
        float acc = bf[j];
        const float invn = 1.0f / NN;
        for (int c = 0; c < HH; c++) acc += pl[b * HH + c] * invn * Wf[c * NCLSS + j];
        z[b][j] = acc;
    }
    __syncthreads();
    if (t < BB) {
        float m = -1e30f;
        for (int j2 = 0; j2 < NCLSS; j2++) m = fmaxf(m, z[t][j2]);
        float s = 0.f;
        for (int j2 = 0; j2 < NCLSS; j2++) s += expf(z[t][j2] - m);
        lse[t] = m + logf(s);
    }
    __syncthreads();
    if (t < BB * NCLSS) {
        float* o = hd ? out + BB * NCLSS + ((size_t)b * 8 + (hd - 1)) * NCLSS + j
                      : out + b * NCLSS + j;
        *o = z[b][j] - lse[b];
    }
}

// ---------------- host ----------------

extern "C" void kernel_launch(void* const* d_in, const int* in_sizes, int n_in, void* d_out,
                              int out_size, void* d_ws, size_t ws_size, hipStream_t stream) {
    const float* x = (const float*)d_in[0];
    const int* ei = (const int*)d_in[1];
    const float* W_in = (const float*)d_in[2];
    const float* b_in = (const float*)d_in[3];
    const float* g_in = (const float*)d_in[4];
    const float* be_in = (const float*)d_in[5];
    const float* shared_W = (const float*)d_in[6];
    const float* shared_b = (const float*)d_in[7];
    const float* shared_g = (const float*)d_in[8];
    const float* shared_be = (const float*)d_in[9];
    const float* main_Wg = (const float*)d_in[10];
    const float* main_bg = (const float*)d_in[11];
    const float* main_g = (const float*)d_in[12];
    const float* main_be = (const float*)d_in[13];
    const float* main_Wf = (const float*)d_in[14];
    const float* main_bf = (const float*)d_in[15];
    const float* aux_Wg = (const float*)d_in[16];
    const float* aux_bg = (const float*)d_in[17];
    const float* aux_g = (const float*)d_in[18];
    const float* aux_be = (const float*)d_in[19];
    const float* aux_Wf = (const float*)d_in[20];
    const float* aux_bf = (const float*)d_in[21];
    float* out = (float*)d_out;

    char* w = (char*)d_ws;
    const size_t BIG = (size_t)RR * HH * 2;
    _Float16* U = (_Float16*)w;  w += BIG;
    _Float16* V = (_Float16*)w;  w += BIG;
    _Float16* P = (_Float16*)w;  w += BIG;
    _Float16* HP = (_Float16*)w; w += BIG;
    float* P0 = (float*)w;       w += (size_t)RR * 2 * 4;
    _Float16* Wh = (_Float16*)w; w += (size_t)11 * 16384 * 2;
    int2* csr = (int2*)w;        w += (size_t)102400 * 8;  // padded CSR (<=99000 entries)
    int* counts = (int*)w;       w += NN * 4;
    int* cursor = (int*)w;       w += NN * 4;
    float* dinv = (float*)w;     w += NN * 4;
    unsigned* d2p = (unsigned*)w; w += NN * 4;
    int* rowptr4 = (int*)w;      w += 36016;
    float* pS1 = (float*)w;      w += (size_t)HH * NTILES * 4;
    float* pS2 = (float*)w;      w += (size_t)HH * NTILES * 4;
    float* pooled = (float*)w;   w += 9 * BB * HH * 4;
    float* tscale = (float*)w;   w += 512;
    float* tshift = (float*)w;   w += 512;
    float* hscale = (float*)w;   w += 512;
    float* hshift = (float*)w;   w += 512;

    hipMemsetAsync(counts, 0, 2 * NN * 4, stream);
    hipMemsetAsync(pooled, 0, 9 * BB * HH * 4, stream);

    k_count<<<(EE + 255) / 256, 256, 0, stream>>>(ei, counts);
    k_dinv<<<(NN + 255) / 256, 256, 0, stream>>>(counts, dinv, d2p);
    k_scan<<<1, 1024, 0, stream>>>(counts, rowptr4);
    k_fill<<<(EE + 255) / 256, 256, 0, stream>>>(ei, rowptr4, cursor, dinv, csr);
    k_pad<<<(NN + 255) / 256, 256, 0, stream>>>(rowptr4, cursor, csr);
    k_wcvt<<<(11 * 16384 + 255) / 256, 256, 0, stream>>>(shared_W, main_Wg, aux_Wg, Wh);

    // L0
    {
        dim3 g((NN + 255) / 256, BB);
        k_prop2<<<g, 256, 0, stream>>>(x, P0, rowptr4, csr, dinv);
        k_mm2<<<NPART0, 256, 0, stream>>>(P0, U, W_in, b_in, pS1, pS2);
        k_bnfin<<<HH, 256, 0, stream>>>(pS1, pS2, NPART0, g_in, be_in, tscale, tshift);
    }

    // shared trunk layers: act -> gather -> mfma -> bnfin
    _Float16* hcur = U;
    _Float16* hnext = V;
    for (int l = 0; l < 2; l++) {
        k_act<<<RR * 16 / 256, 256, 0, stream>>>(hcur, HP, tscale, tshift);
        k_gather<<<8 * 2250, 256, 0, stream>>>(HP, P, rowptr4, csr, d2p, 0);
        k_mfma2<<<NTILES, 256, 0, stream>>>(P, hnext, Wh + (size_t)l * 16384,
                                            shared_b + l * HH, pS1, pS2);
        k_bnfin<<<HH, 256, 0, stream>>>(pS1, pS2, NTILES, shared_g + l * HH, shared_be + l * HH,
                                        tscale, tshift);
        _Float16* tmp = hcur; hcur = hnext; hnext = tmp;
    }

    // activate trunk output once; all 9 heads share it
    k_act<<<RR * 16 / 256, 256, 0, stream>>>(hcur, HP, tscale, tshift);

    // heads
    for (int hd = 0; hd < 9; hd++) {
        int shift = hd * 1000;
        const _Float16* Wg = Wh + (size_t)(2 + hd) * 16384;
        const float* bg = (hd == 0) ? main_bg : aux_bg + (hd - 1) * HH;
        const float* gg = (hd == 0) ? main_g : aux_g + (hd - 1) * HH;
        const float* be = (hd == 0) ? main_be : aux_be + (hd - 1) * HH;

        k_gather<<<8 * 2250, 256, 0, stream>>>(HP, P, rowptr4, csr, d2p, shift);
        k_mfma2<<<NTILES, 256, 0, stream>>>(P, hnext, Wg, bg, pS1, pS2);
        k_bnfin<<<HH, 256, 0, stream>>>(pS1, pS2, NTILES, gg, be, hscale, hshift);
        dim3 gp(36, BB);
        k_relu_pool<<<gp, 256, 0, stream>>>(hnext, hscale, hshift, pooled + (size_t)hd * BB * HH);
    }
    k_head_all<<<9, 192, 0, stream>>>(pooled, main_Wf, main_bf, aux_Wf, aux_bf, out);
}

// Round 13
// 1016.784 us; speedup vs baseline: 1.5546x; 1.1009x over previous
//
#include <hip/hip_runtime.h>
#include <hip/hip_bf16.h>
#include <math.h>

#define BB 16
#define TT 360
#define VV 25
#define NN 9000
#define EE 72000
#define HH 128
#define RR (NN * BB)       // 144000 rows total
#define CROWS 18000        // rows per chunk (9000 nodes x 2 batches)
#define NTILES (RR / 64)   // 2250 tiles of 64 rows for k_mfma2 (exact)
#define NPART0 563         // partial-stats blocks for k_mm2 (L0)
#define NCLSS 12
#define EPSB 1e-5f

// chunked activation layout: row R(n,b) = (b>>1)*CROWS + n*2 + (b&1)

typedef _Float16 h4v __attribute__((ext_vector_type(4)));
typedef _Float16 h8v __attribute__((ext_vector_type(8)));
typedef float float16v __attribute__((ext_vector_type(16)));

__device__ __forceinline__ h8v cf8(unsigned packed) {
    uint4 cc = {packed, packed, packed, packed};
    return __builtin_bit_cast(h8v, cc);
}

// ---------------- graph preprocessing ----------------

__global__ void k_count(const int* __restrict__ ei, int* __restrict__ counts) {
    int e = blockIdx.x * 256 + threadIdx.x;
    if (e < EE) atomicAdd(&counts[ei[EE + e]], 1);
}

// dinv (f32) + packed half2 of dinv^2 (self-loop coef)
__global__ void k_dinv(const int* __restrict__ counts, float* __restrict__ dinv,
                       unsigned* __restrict__ d2p) {
    int n = blockIdx.x * 256 + threadIdx.x;
    if (n >= NN) return;
    float di = rsqrtf((float)(counts[n] + 1));
    dinv[n] = di;
    _Float16 d2 = (_Float16)(di * di);
    unsigned short u = __builtin_bit_cast(unsigned short, d2);
    d2p[n] = (unsigned)u | ((unsigned)u << 16);
}

// exclusive prefix over padded degrees deg4 = (deg+3)&~3
__global__ void k_scan(const int* __restrict__ counts, int* __restrict__ rowptr4) {
    __shared__ int part[1024];
    int t = threadIdx.x;
    int base = t * 9;
    int loc[9];
    int s = 0;
#pragma unroll
    for (int i = 0; i < 9; i++) {
        int idx = base + i;
        int v = (idx < NN) ? ((counts[idx] + 3) & ~3) : 0;
        loc[i] = s;
        s += v;
    }
    part[t] = s;
    __syncthreads();
    for (int d = 1; d < 1024; d <<= 1) {
        int v = (t >= d) ? part[t - d] : 0;
        __syncthreads();
        part[t] += v;
        __syncthreads();
    }
    int excl = (t == 0) ? 0 : part[t - 1];
#pragma unroll
    for (int i = 0; i < 9; i++) {
        int idx = base + i;
        if (idx < NN) rowptr4[idx] = excl + loc[i];
    }
    if (t == 1023) rowptr4[NN] = part[1023];
}

// csr entry: {src, coef packed as half2(cf,cf)}
__global__ void k_fill(const int* __restrict__ ei, const int* __restrict__ rowptr4,
                       int* __restrict__ cursor, const float* __restrict__ dinv,
                       int2* __restrict__ csr) {
    int e = blockIdx.x * 256 + threadIdx.x;
    if (e >= EE) return;
    int s = ei[e], d = ei[EE + e];
    int slot = rowptr4[d] + atomicAdd(&cursor[d], 1);
    _Float16 cfh = (_Float16)(dinv[s] * dinv[d]);
    unsigned short u = __builtin_bit_cast(unsigned short, cfh);
    int2 e2;
    e2.x = s;
    e2.y = (int)((unsigned)u | ((unsigned)u << 16));
    csr[slot] = e2;
}

// fill pad slots with {n, 0} (self row, zero coef)
__global__ void k_pad(const int* __restrict__ rowptr4, const int* __restrict__ cursor,
                      int2* __restrict__ csr) {
    int n = blockIdx.x * 256 + threadIdx.x;
    if (n >= NN) return;
    int beg = rowptr4[n] + cursor[n];
    int end = rowptr4[n + 1];
    int2 z;
    z.x = n;
    z.y = 0;
    for (int e = beg; e < end; e++) csr[e] = z;
}

// pre-convert the 11 layer weight matrices to f16 W^T images: Wh[l][c*128+k]
__global__ void k_wcvt(const float* __restrict__ sW, const float* __restrict__ mW,
                       const float* __restrict__ aW, _Float16* __restrict__ Wh) {
    int idx = blockIdx.x * 256 + threadIdx.x;
    if (idx >= 11 * 16384) return;
    int l = idx >> 14, r = idx & 16383;
    int k = r >> 7, c = r & 127;
    const float* src = (l < 2) ? sW + (size_t)l * 16384
                               : ((l == 2) ? mW : aW + (size_t)(l - 3) * 16384);
    Wh[(size_t)l * 16384 + c * 128 + k] = (_Float16)src[k * 128 + c];
}

// ---------------- L0 propagation of raw x (2 channels, f32) ----------------
__global__ void k_prop2(const float* __restrict__ x, float* __restrict__ P0,
                        const int* __restrict__ rowptr4, const int2* __restrict__ csr,
                        const float* __restrict__ dinv) {
    int n = blockIdx.x * 256 + threadIdx.x;
    if (n >= NN) return;
    int b = blockIdx.y;
    const float* xb = x + (size_t)b * NN * 2;
    float d2 = dinv[n] * dinv[n];
    float a0 = d2 * xb[2 * n], a1 = d2 * xb[2 * n + 1];
    int beg = rowptr4[n], end = rowptr4[n + 1];
    for (int j = beg; j < end; j++) {
        int2 e2 = csr[j];
        int s = e2.x;
        unsigned short u = (unsigned short)((unsigned)e2.y & 0xffffu);
        float cf = (float)__builtin_bit_cast(_Float16, u);
        a0 += cf * xb[2 * s];
        a1 += cf * xb[2 * s + 1];
    }
    float* Pb = P0 + (size_t)(n * BB + b) * 2;
    Pb[0] = a0;
    Pb[1] = a1;
}

// L0 matmul (K=2), writes chunked f16 layout, fused BN partial stats pS[c][part].
__global__ void __launch_bounds__(256) k_mm2(const float* __restrict__ P0,
                                             _Float16* __restrict__ A,
                                             const float* __restrict__ W,
                                             const float* __restrict__ bias,
                                             float* __restrict__ pS1, float* __restrict__ pS2) {
    __shared__ float L1[256][8], L2[256][8];
    int t = threadIdx.x;
    int cg = t & 15, c8 = cg * 8;
    float wv0[8], wv1[8], bv[8];
#pragma unroll
    for (int j = 0; j < 8; j++) {
        wv0[j] = W[c8 + j];
        wv1[j] = W[HH + c8 + j];
        bv[j] = bias[c8 + j];
    }
    float s1[8], s2[8];
#pragma unroll
    for (int j = 0; j < 8; j++) { s1[j] = 0.f; s2[j] = 0.f; }
    for (int idx = blockIdx.x * 256 + t; idx < RR * 16; idx += gridDim.x * 256) {
        int Rr = idx >> 4;
        int q = Rr / CROWS;
        int rr = Rr - q * CROWS;
        int n = rr >> 1;
        int b = q * 2 + (rr & 1);
        float p0 = P0[((size_t)n * BB + b) * 2], p1 = P0[((size_t)n * BB + b) * 2 + 1];
        h8v o;
#pragma unroll
        for (int j = 0; j < 8; j++) {
            float v = p0 * wv0[j] + p1 * wv1[j] + bv[j];
            s1[j] += v;
            s2[j] += v * v;
            o[j] = (_Float16)v;
        }
        *(h8v*)(A + (size_t)Rr * HH + c8) = o;
    }
#pragma unroll
    for (int j = 0; j < 8; j++) { L1[t][j] = s1[j]; L2[t][j] = s2[j]; }
    __syncthreads();
    if (t < 16) {
#pragma unroll
        for (int g = 1; g < 16; g++)
#pragma unroll
            for (int j = 0; j < 8; j++) {
                s1[j] = (g == 1 ? L1[t][j] : s1[j]) + L1[t + 16 * g][j];
                s2[j] = (g == 1 ? L2[t][j] : s2[j]) + L2[t + 16 * g][j];
            }
#pragma unroll
        for (int j = 0; j < 8; j++) {
            pS1[(size_t)(t * 8 + j) * NPART0 + blockIdx.x] = s1[j];
            pS2[(size_t)(t * 8 + j) * NPART0 + blockIdx.x] = s2[j];
        }
    }
}

// ---------------- activation pass: h' = relu(A*sc+sh), f16 -> f16 ----------------
__global__ void __launch_bounds__(256) k_act(const _Float16* __restrict__ A,
                                             _Float16* __restrict__ HP,
                                             const float* __restrict__ scale,
                                             const float* __restrict__ shiftv) {
    int i = blockIdx.x * 256 + threadIdx.x;  // over RR*16 groups of 8 channels
    int c8 = (i & 15) * 8;
    h8v v = *(const h8v*)(A + (size_t)i * 8);
    h8v o;
#pragma unroll
    for (int j = 0; j < 8; j++) {
        float f = (float)v[j] * scale[c8 + j] + shiftv[c8 + j];
        o[j] = (_Float16)fmaxf(f, 0.f);
    }
    *(h8v*)(HP + (size_t)i * 8) = o;
}

// ---------------- pure gather: P = A_hat * h', paired-edge loads, 8 edges in flight ----
// chunked (2 batches = 4.6MB L2-resident, blockIdx&7 XCD-routed); wave-per-node.
// lanes 0-31: even edges, lanes 32-63: odd edges; 16B/lane; final shfl_xor(32) combine.
__global__ void __launch_bounds__(256) k_gather(const _Float16* __restrict__ h,
                                                _Float16* __restrict__ P,
                                                const int* __restrict__ rowptr4,
                                                const int2* __restrict__ csr,
                                                const unsigned* __restrict__ d2p, int shn) {
    int t = threadIdx.x;
    int q = blockIdx.x & 7;     // chunk -> XCD routing
    int ng4 = blockIdx.x >> 3;  // 0..2249
    int wv = t >> 6, l = t & 63;
    int n = ng4 * 4 + wv;       // wave's node (2250*4 = 9000 exact)
    int half = l >> 5, li = l & 31;
    // lane's 16B (8 f16) within a node slab (2 batch rows x 128 ch = 512B)
    const _Float16* hb = h + (size_t)q * CROWS * HH + (size_t)li * 8;
    int pn = n + shn;
    if (pn >= NN) pn -= NN;
    h8v acc;
    {
        h8v v = *(const h8v*)(hb + (size_t)pn * 2 * HH);
        acc = v * cf8(half ? 0u : d2p[n]);  // self counted once (lower half)
    }
    int beg = rowptr4[n], end = rowptr4[n + 1];  // multiples of 4
    int e = beg;
    for (; e + 8 <= end; e += 8) {
        int4 m0 = *(const int4*)(csr + e);      // edges e,   e+1
        int4 m1 = *(const int4*)(csr + e + 2);  // edges e+2, e+3
        int4 m2 = *(const int4*)(csr + e + 4);  // edges e+4, e+5
        int4 m3 = *(const int4*)(csr + e + 6);  // edges e+6, e+7
        int s0 = (half ? m0.z : m0.x) + shn; if (s0 >= NN) s0 -= NN;
        int s1 = (half ? m1.z : m1.x) + shn; if (s1 >= NN) s1 -= NN;
        int s2 = (half ? m2.z : m2.x) + shn; if (s2 >= NN) s2 -= NN;
        int s3 = (half ? m3.z : m3.x) + shn; if (s3 >= NN) s3 -= NN;
        h8v v0 = *(const h8v*)(hb + (size_t)s0 * 2 * HH);  // 4 loads = 8 edges in flight
        h8v v1 = *(const h8v*)(hb + (size_t)s1 * 2 * HH);
        h8v v2 = *(const h8v*)(hb + (size_t)s2 * 2 * HH);
        h8v v3 = *(const h8v*)(hb + (size_t)s3 * 2 * HH);
        acc += v0 * cf8((unsigned)(half ? m0.w : m0.y));
        acc += v1 * cf8((unsigned)(half ? m1.w : m1.y));
        acc += v2 * cf8((unsigned)(half ? m2.w : m2.y));
        acc += v3 * cf8((unsigned)(half ? m3.w : m3.y));
    }
    if (e < end) {  // exactly 4 edges remain
        int4 m0 = *(const int4*)(csr + e);
        int4 m1 = *(const int4*)(csr + e + 2);
        int s0 = (half ? m0.z : m0.x) + shn; if (s0 >= NN) s0 -= NN;
        int s1 = (half ? m1.z : m1.x) + shn; if (s1 >= NN) s1 -= NN;
        h8v v0 = *(const h8v*)(hb + (size_t)s0 * 2 * HH);
        h8v v1 = *(const h8v*)(hb + (size_t)s1 * 2 * HH);
        acc += v0 * cf8((unsigned)(half ? m0.w : m0.y));
        acc += v1 * cf8((unsigned)(half ? m1.w : m1.y));
    }
    // combine even/odd-edge halves: acc += acc from lane l^32
    int4 ai = __builtin_bit_cast(int4, acc);
    int4 bi4;
    bi4.x = __shfl_xor(ai.x, 32, 64);
    bi4.y = __shfl_xor(ai.y, 32, 64);
    bi4.z = __shfl_xor(ai.z, 32, 64);
    bi4.w = __shfl_xor(ai.w, 32, 64);
    acc += __builtin_bit_cast(h8v, bi4);
    if (half == 0) {
        *(h8v*)(P + ((size_t)q * CROWS + (size_t)n * 2) * HH + (size_t)li * 8) = acc;
    }
}

// ---------------- dense MFMA matmul (f16): A = P*W + bias, fused BN partial stats ----
__global__ void __launch_bounds__(256) k_mfma2(const _Float16* __restrict__ P,
                                               _Float16* __restrict__ A,
                                               const _Float16* __restrict__ Wh,
                                               const float* __restrict__ bias,
                                               float* __restrict__ pS1,
                                               float* __restrict__ pS2) {
    __shared__ float rb1[4][128], rb2[4][128];  // 4 KB stats reduction
    int t = threadIdx.x;
    int w = t >> 6, l = t & 63;
    int rw = w >> 1, cw = w & 1;  // 32-row half x 64-col half
    int lr = l & 31, hi = l >> 5;
    size_t rbase = (size_t)blockIdx.x * 64;
    const _Float16* Pr0 = P + (rbase + rw * 32 + lr) * HH;
    const _Float16* Wc0 = Wh + (size_t)(cw * 64 + lr) * HH;
    const _Float16* Wc1 = Wh + (size_t)(cw * 64 + 32 + lr) * HH;
    float16v acc2[2];
#pragma unroll
    for (int ct = 0; ct < 2; ct++) acc2[ct] = (float16v)(0.0f);
#pragma unroll
    for (int ks = 0; ks < 8; ks++) {
        int koff = ks * 16 + hi * 8;
        h8v a0 = *(const h8v*)(Pr0 + koff);
        h8v b0 = *(const h8v*)(Wc0 + koff);
        h8v b1 = *(const h8v*)(Wc1 + koff);
        acc2[0] = __builtin_amdgcn_mfma_f32_32x32x16_f16(a0, b0, acc2[0], 0, 0, 0);
        acc2[1] = __builtin_amdgcn_mfma_f32_32x32x16_f16(a0, b1, acc2[1], 0, 0, 0);
    }
    // epilogue: bias, stats, store f16
    float bv[2] = {bias[cw * 64 + lr], bias[cw * 64 + 32 + lr]};
    float s1a[2] = {0.f, 0.f}, s2a[2] = {0.f, 0.f};
#pragma unroll
    for (int ct = 0; ct < 2; ct++) {
        int c = cw * 64 + ct * 32 + lr;
#pragma unroll
        for (int g = 0; g < 16; g++) {
            int row = rw * 32 + (g & 3) + 8 * (g >> 2) + 4 * hi;
            float v = acc2[ct][g] + bv[ct];
            s1a[ct] += v;
            s2a[ct] += v * v;
            A[(rbase + row) * HH + c] = (_Float16)v;
        }
    }
    int slot = rw * 2 + hi;
#pragma unroll
    for (int ct = 0; ct < 2; ct++) {
        int cidx = cw * 64 + ct * 32 + lr;
        rb1[slot][cidx] = s1a[ct];
        rb2[slot][cidx] = s2a[ct];
    }
    __syncthreads();
    if (t < 128) {
        float a1 = rb1[0][t] + rb1[1][t] + rb1[2][t] + rb1[3][t];
        float a2 = rb2[0][t] + rb2[1][t] + rb2[2][t] + rb2[3][t];
        pS1[(size_t)t * NTILES + blockIdx.x] = a1;  // transposed: [channel][tile]
        pS2[(size_t)t * NTILES + blockIdx.x] = a2;
    }
}

// finalize BN affine from transposed partials: one block per channel, coalesced rows
__global__ void __launch_bounds__(256) k_bnfin(const float* __restrict__ pS1,
                                               const float* __restrict__ pS2, int npart,
                                               const float* __restrict__ g,
                                               const float* __restrict__ be,
                                               float* __restrict__ scale,
                                               float* __restrict__ shiftv) {
    __shared__ float R1[256], R2[256];
    int c = blockIdx.x;
    int t = threadIdx.x;
    const float* p1 = pS1 + (size_t)c * npart;
    const float* p2 = pS2 + (size_t)c * npart;
    float s1 = 0.f, s2 = 0.f;
    for (int i = t; i < npart; i += 256) {
        s1 += p1[i];
        s2 += p2[i];
    }
    R1[t] = s1;
    R2[t] = s2;
    __syncthreads();
    for (int d = 128; d > 0; d >>= 1) {
        if (t < d) {
            R1[t] += R1[t + d];
            R2[t] += R2[t + d];
        }
        __syncthreads();
    }
    if (t == 0) {
        float inv = 1.0f / (float)RR;
        float mu = R1[0] * inv;
        float var = R2[0] * inv - mu * mu;
        float sc = g[c] * rsqrtf(var + EPSB);
        scale[c] = sc;
        shiftv[c] = be[c] - mu * sc;
    }
}

// fused BN-affine + ReLU + mean-pool (per head), chunked f16 reads
__global__ void __launch_bounds__(256) k_relu_pool(const _Float16* __restrict__ A,
                                                   const float* __restrict__ scale,
                                                   const float* __restrict__ shiftv,
                                                   float* __restrict__ pooled) {
    __shared__ float L[256][8];
    int t = threadIdx.x;
    int b = blockIdx.y;
    int n0 = blockIdx.x * 250;
    int ng = t >> 4, c8 = (t & 15) * 8;
    float sc[8], sh[8];
#pragma unroll
    for (int j = 0; j < 8; j++) {
        sc[j] = scale[c8 + j];
        sh[j] = shiftv[c8 + j];
    }
    const _Float16* Ab = A + ((size_t)(b >> 1) * CROWS + (b & 1)) * HH;
    float acc[8];
#pragma unroll
    for (int j = 0; j < 8; j++) acc[j] = 0.f;
    for (int n = n0 + ng; n < n0 + 250; n += 16) {
        h8v v = *(const h8v*)(Ab + (size_t)n * 2 * HH + c8);
#pragma unroll
        for (int j = 0; j < 8; j++) {
            float f = (float)v[j] * sc[j] + sh[j];
            acc[j] += fmaxf(f, 0.f);
        }
    }
#pragma unroll
    for (int j = 0; j < 8; j++) L[t][j] = acc[j];
    __syncthreads();
    if (ng == 0) {
#pragma unroll
        for (int g = 1; g < 16; g++)
#pragma unroll
            for (int j = 0; j < 8; j++) acc[j] += L[t + 16 * g][j];
#pragma unroll
        for (int j = 0; j < 8; j++) atomicAdd(&pooled[b * HH + t * 8 + j], acc[j]);
    }
}

// all 9 heads: linear + log_softmax
__global__ void __launch_bounds__(192) k_head_all(const float* __restrict__ pooled,
                                                  const float* __restrict__ main_Wf,
                                                  const float* __restrict__ main_bf,
                                                  const float* __restrict__ aux_Wf,
                                                  const float* __restrict__ aux_bf,
                                                  float* __restrict__ out) {
    int hd = blockIdx.x;
    const float* Wf = hd ? aux_Wf + (size_t)(hd - 1) * HH * NCLSS : main_Wf;
    const float* bf = hd ? aux_bf + (hd - 1) * NCLSS : main_bf;
    const float* pl = pooled + (size_t)hd * BB * HH;
    __shared__ float z[BB][NCLSS];
    __shared__ float lse[BB];
    int t = threadIdx.x;
    int b = t / NCLSS, j = t % NCLSS;
    if (t < BB * NCLSS) {
        float acc = bf[j];
        const float invn = 1.0f / NN;
        for (int c = 0; c < HH; c++) acc += pl[b * HH + c] * invn * Wf[c * NCLSS + j];
        z[b][j] = acc;
    }
    __syncthreads();
    if (t < BB) {
        float m = -1e30f;
        for (int j2 = 0; j2 < NCLSS; j2++) m = fmaxf(m, z[t][j2]);
        float s = 0.f;
        for (int j2 = 0; j2 < NCLSS; j2++) s += expf(z[t][j2] - m);
        lse[t] = m + logf(s);
    }
    __syncthreads();
    if (t < BB * NCLSS) {
        float* o = hd ? out + BB * NCLSS + ((size_t)b * 8 + (hd - 1)) * NCLSS + j
                      : out + b * NCLSS + j;
        *o = z[b][j] - lse[b];
    }
}

// ---------------- host ----------------

extern "C" void kernel_launch(void* const* d_in, const int* in_sizes, int n_in, void* d_out,
                              int out_size, void* d_ws, size_t ws_size, hipStream_t stream) {
    const float* x = (const float*)d_in[0];
    const int* ei = (const int*)d_in[1];
    const float* W_in = (const float*)d_in[2];
    const float* b_in = (const float*)d_in[3];
    const float* g_in = (const float*)d_in[4];
    const float* be_in = (const float*)d_in[5];
    const float* shared_W = (const float*)d_in[6];
    const float* shared_b = (const float*)d_in[7];
    const float* shared_g = (const float*)d_in[8];
    const float* shared_be = (const float*)d_in[9];
    const float* main_Wg = (const float*)d_in[10];
    const float* main_bg = (const float*)d_in[11];
    const float* main_g = (const float*)d_in[12];
    const float* main_be = (const float*)d_in[13];
    const float* main_Wf = (const float*)d_in[14];
    const float* main_bf = (const float*)d_in[15];
    const float* aux_Wg = (const float*)d_in[16];
    const float* aux_bg = (const float*)d_in[17];
    const float* aux_g = (const float*)d_in[18];
    const float* aux_be = (const float*)d_in[19];
    const float* aux_Wf = (const float*)d_in[20];
    const float* aux_bf = (const float*)d_in[21];
    float* out = (float*)d_out;

    char* w = (char*)d_ws;
    const size_t BIG = (size_t)RR * HH * 2;
    _Float16* U = (_Float16*)w;  w += BIG;
    _Float16* V = (_Float16*)w;  w += BIG;
    _Float16* P = (_Float16*)w;  w += BIG;
    _Float16* HP = (_Float16*)w; w += BIG;
    float* P0 = (float*)w;       w += (size_t)RR * 2 * 4;
    _Float16* Wh = (_Float16*)w; w += (size_t)11 * 16384 * 2;
    int2* csr = (int2*)w;        w += (size_t)102400 * 8;  // padded CSR (<=99000 entries)
    int* counts = (int*)w;       w += NN * 4;
    int* cursor = (int*)w;       w += NN * 4;
    float* dinv = (float*)w;     w += NN * 4;
    unsigned* d2p = (unsigned*)w; w += NN * 4;
    int* rowptr4 = (int*)w;      w += 36016;
    float* pS1 = (float*)w;      w += (size_t)HH * NTILES * 4;
    float* pS2 = (float*)w;      w += (size_t)HH * NTILES * 4;
    float* pooled = (float*)w;   w += 9 * BB * HH * 4;
    float* tscale = (float*)w;   w += 512;
    float* tshift = (float*)w;   w += 512;
    float* hscale = (float*)w;   w += 512;
    float* hshift = (float*)w;   w += 512;

    hipMemsetAsync(counts, 0, 2 * NN * 4, stream);
    hipMemsetAsync(pooled, 0, 9 * BB * HH * 4, stream);

    k_count<<<(EE + 255) / 256, 256, 0, stream>>>(ei, counts);
    k_dinv<<<(NN + 255) / 256, 256, 0, stream>>>(counts, dinv, d2p);
    k_scan<<<1, 1024, 0, stream>>>(counts, rowptr4);
    k_fill<<<(EE + 255) / 256, 256, 0, stream>>>(ei, rowptr4, cursor, dinv, csr);
    k_pad<<<(NN + 255) / 256, 256, 0, stream>>>(rowptr4, cursor, csr);
    k_wcvt<<<(11 * 16384 + 255) / 256, 256, 0, stream>>>(shared_W, main_Wg, aux_Wg, Wh);

    // L0
    {
        dim3 g((NN + 255) / 256, BB);
        k_prop2<<<g, 256, 0, stream>>>(x, P0, rowptr4, csr, dinv);
        k_mm2<<<NPART0, 256, 0, stream>>>(P0, U, W_in, b_in, pS1, pS2);
        k_bnfin<<<HH, 256, 0, stream>>>(pS1, pS2, NPART0, g_in, be_in, tscale, tshift);
    }

    // shared trunk layers: act -> gather -> mfma -> bnfin
    _Float16* hcur = U;
    _Float16* hnext = V;
    for (int l = 0; l < 2; l++) {
        k_act<<<RR * 16 / 256, 256, 0, stream>>>(hcur, HP, tscale, tshift);
        k_gather<<<8 * 2250, 256, 0, stream>>>(HP, P, rowptr4, csr, d2p, 0);
        k_mfma2<<<NTILES, 256, 0, stream>>>(P, hnext, Wh + (size_t)l * 16384,
                                            shared_b + l * HH, pS1, pS2);
        k_bnfin<<<HH, 256, 0, stream>>>(pS1, pS2, NTILES, shared_g + l * HH, shared_be + l * HH,
                                        tscale, tshift);
        _Float16* tmp = hcur; hcur = hnext; hnext = tmp;
    }

    // activate trunk output once; all 9 heads share it
    k_act<<<RR * 16 / 256, 256, 0, stream>>>(hcur, HP, tscale, tshift);

    // heads
    for (int hd = 0; hd < 9; hd++) {
        int shift = hd * 1000;
        const _Float16* Wg = Wh + (size_t)(2 + hd) * 16384;
        const float* bg = (hd == 0) ? main_bg : aux_bg + (hd - 1) * HH;
        const float* gg = (hd == 0) ? main_g : aux_g + (hd - 1) * HH;
        const float* be = (hd == 0) ? main_be : aux_be + (hd - 1) * HH;

        k_gather<<<8 * 2250, 256, 0, stream>>>(HP, P, rowptr4, csr, d2p, shift);
        k_mfma2<<<NTILES, 256, 0, stream>>>(P, hnext, Wg, bg, pS1, pS2);
        k_bnfin<<<HH, 256, 0, stream>>>(pS1, pS2, NTILES, gg, be, hscale, hshift);
        dim3 gp(36, BB);
        k_relu_pool<<<gp, 256, 0, stream>>>(hnext, hscale, hshift, pooled + (size_t)hd * BB * HH);
    }
    k_head_all<<<9, 192, 0, stream>>>(pooled, main_Wf, main_bf, aux_Wf, aux_bf, out);
}